// Round 6
// baseline (731.215 us; speedup 1.0000x reference)
//
#include <hip/hip_runtime.h>
#include <math.h>

#define DIV_UP(a,b) (((a)+(b)-1)/(b))

static constexpr int Bb = 4, Tt = 256, Mm = 512, Dd = 1024, Vv = 50257;
static constexpr int NN = Bb * Tt;   // 1024 flattened (b,t) rows

typedef __attribute__((ext_vector_type(8))) short short8v;
typedef __attribute__((ext_vector_type(4))) float float4v;
typedef unsigned short ushort;

// fp32 -> bf16 RNE (bit trick, branchless)
static __device__ __forceinline__ ushort f2bf(float f) {
    unsigned u = __float_as_uint(f);
    u += 0x7FFFu + ((u >> 16) & 1u);
    return (ushort)(u >> 16);
}
static __device__ __forceinline__ float bf2f(ushort h) {
    return __uint_as_float(((unsigned)h) << 16);
}

// async 16B global -> LDS (wave-uniform base + lane*16 dest)
static __device__ __forceinline__ void gload16(const void* g, void* l) {
    __builtin_amdgcn_global_load_lds(
        (const __attribute__((address_space(1))) unsigned int*)g,
        (__attribute__((address_space(3))) unsigned int*)l, 16, 0, 0);
}

// ---- fp32 -> bf16 cast, 8/thread --------------------------------------------
__launch_bounds__(256)
__global__ void cast_bf16(const float* __restrict__ src, ushort* __restrict__ dst, long n8)
{
    for (long i = blockIdx.x * 256 + threadIdx.x; i < n8; i += (long)gridDim.x * 256) {
        const float4 v0 = *(const float4*)&src[i * 8];
        const float4 v1 = *(const float4*)&src[i * 8 + 4];
        short8v t;
        t[0]=f2bf(v0.x); t[1]=f2bf(v0.y); t[2]=f2bf(v0.z); t[3]=f2bf(v0.w);
        t[4]=f2bf(v1.x); t[5]=f2bf(v1.y); t[6]=f2bf(v1.z); t[7]=f2bf(v1.w);
        *(short8v*)&dst[i * 8] = t;
    }
}

// ---- fp32 -> (hi, lo) bf16 split, 8/thread ----------------------------------
__launch_bounds__(256)
__global__ void split_cast(const float* __restrict__ src, ushort* __restrict__ hi,
                           ushort* __restrict__ lo, long n8)
{
    for (long i = blockIdx.x * 256 + threadIdx.x; i < n8; i += (long)gridDim.x * 256) {
        short8v th, tl;
#pragma unroll
        for (int q = 0; q < 8; ++q) {
            float v = src[i * 8 + q];
            ushort h = f2bf(v);
            th[q] = h;
            tl[q] = f2bf(v - bf2f(h));
        }
        *(short8v*)&hi[i * 8] = th;
        *(short8v*)&lo[i * 8] = tl;
    }
}

// ---- batched transpose: in[b] R x C fp32 -> out[b] C x R bf16 (hi, opt lo) --
__launch_bounds__(256)
__global__ void transpose_split(const float* __restrict__ in, ushort* __restrict__ oh,
                                ushort* __restrict__ ol, int R, int C)
{
    __shared__ float t[32][33];
    const int bz = blockIdx.z;
    in += (long)bz * R * C;
    oh += (long)bz * R * C;
    if (ol) ol += (long)bz * R * C;
    const int tx = threadIdx.x & 31, ty = threadIdx.x >> 5;
    const int r0 = blockIdx.y * 32, c0 = blockIdx.x * 32;
#pragma unroll
    for (int k = 0; k < 4; ++k)
        t[ty + k * 8][tx] = in[(long)(r0 + ty + k * 8) * C + c0 + tx];
    __syncthreads();
#pragma unroll
    for (int k = 0; k < 4; ++k) {
        float v = t[tx][ty + k * 8];
        ushort h = f2bf(v);
        long o = (long)(c0 + ty + k * 8) * R + r0 + tx;
        oh[o] = h;
        if (ol) ol[o] = f2bf(v - bf2f(h));
    }
}

// ---------------------------------------------------------------------------
// Unified bf16 MFMA GEMM (NT): C[i,j] = sum_k A[i,k]*B[j,k]
// SPLIT: 3-pass split-bf16 (Ah*Bh + Ah*Bl + Al*Bh), proven 2-buffer drain loop.
// non-SPLIT: ring-3 LDS buffers, counted vmcnt, raw barriers (T3+T4+T5).
// Source addrs pre-swizzled so ds_read_b128 frag reads are bank-balanced.
// epi: 0 = fp32 C; 1 = fp32 C + bias + rowsum[i] += sum_j exp(x), via
//      LDS-transposed coalesced row stores; 2 = pgacc[i] += sum tanh(x+b)*Wg;
//      4 = bf16 C write.
// xcd_jtiles > 0: flat-grid XCD swizzle (8 M-tiles fast per XCD chunk).
// ---------------------------------------------------------------------------
template<bool SPLIT>
__launch_bounds__(256)
__global__ void gemm_mx(const ushort* __restrict__ Ah, const ushort* __restrict__ Al,
                        const ushort* __restrict__ Bh, const ushort* __restrict__ Bl,
                        const ushort* __restrict__ A2, int ksplit, int lda2,
                        const float* __restrict__ bias,
                        float* __restrict__ Cf, ushort* __restrict__ C16,
                        float* __restrict__ aux, const float* __restrict__ Wg,
                        int Ncols, int K, int lda, int ldb, int ldc,
                        long sA, long sB, long sC, int epi, int xcd_jtiles)
{
    constexpr int TILE = 4096;   // ushorts per 128x32 bf16 tile (8 KB)
    // SPLIT: 2 buffers x 4 tiles; non-split: 3-ring x 2 tiles (48 KB)
    __shared__ __align__(16) ushort lds[SPLIT ? 8 * TILE : 6 * TILE];

    int mt, jt, bz;
    if (xcd_jtiles > 0) {
        const int id = blockIdx.x;
        const int s = id >> 3;
        jt = (id & 7) * ((xcd_jtiles + 7) >> 3) + (s >> 3);
        mt = s & 7;
        bz = 0;
        if (jt >= xcd_jtiles) return;
    } else { jt = blockIdx.x; mt = blockIdx.y; bz = blockIdx.z; }

    const int tid  = threadIdx.x;
    const int lane = tid & 63;
    const int wave = tid >> 6;
    const int mw = (wave >> 1) * 64, nw = (wave & 1) * 64;
    const int i0 = mt * 128, j0 = jt * 128;

    const int srow = tid >> 2;
    const int soff = ((tid & 3) ^ ((srow >> 1) & 3)) * 8;   // swizzled source slot

    const long Ab = (long)bz * sA;
    const long Bz = (long)bz * sB;
    const long ar0 = i0 + srow, ar1 = i0 + 64 + srow;
    long br0 = j0 + srow;      if (br0 > Ncols - 1) br0 = Ncols - 1;
    long br1 = j0 + 64 + srow; if (br1 > Ncols - 1) br1 = Ncols - 1;

    const int NT = K >> 5;

    float4v acc[4][4];
#pragma unroll
    for (int m = 0; m < 4; ++m)
#pragma unroll
        for (int n = 0; n < 4; ++n) acc[m][n] = (float4v){0.f, 0.f, 0.f, 0.f};

#define STG(dst, src, kc) \
    gload16(&(src)[ar0 * lA + (kc) + soff], (dst) + tid * 8); \
    gload16(&(src)[ar1 * lA + (kc) + soff], (dst) + 2048 + tid * 8);
#define STGB(dst, src, kc) \
    gload16(&(src)[br0 * ldb + (kc) + soff], (dst) + tid * 8); \
    gload16(&(src)[br1 * ldb + (kc) + soff], (dst) + 2048 + tid * 8);

#define STAGE_ALL(buf, kc)                                                     \
    {                                                                          \
        const bool sec = (kc) >= ksplit;                                       \
        const int  kk  = sec ? (kc) - ksplit : (kc);                           \
        const int  lA  = sec ? lda2 : lda;                                     \
        constexpr int BS = SPLIT ? 4 * TILE : 2 * TILE;                        \
        ushort* dA = lds + (buf) * BS;                                         \
        if (SPLIT) {                                                           \
            STG(dA, Ah + Ab, kk);                                              \
            STG(dA + TILE, Al + Ab, kk);                                       \
            STGB(dA + 2 * TILE, Bh + Bz, kc);                                  \
            STGB(dA + 3 * TILE, Bl + Bz, kc);                                  \
        } else {                                                               \
            const ushort* As = sec ? A2 : Ah;                                  \
            STG(dA, As + Ab, kk);                                              \
            STGB(dA + TILE, Bh + Bz, kc);                                      \
        }                                                                      \
    }

    const int fr = lane & 15;
    const int rdsw = (((lane >> 4) ^ ((fr >> 1) & 3))) * 8;  // swizzled read slot

    if constexpr (SPLIT) {
        // ---- proven 2-buffer drain loop ----
        STAGE_ALL(0, 0);
        __syncthreads();
        for (int t = 0; t < NT; ++t) {
            const int cur = t & 1;
            const ushort* Acur = lds + cur * 4 * TILE;
            const ushort* Bcur = Acur + 2 * TILE;

            if (t + 1 < NT) STAGE_ALL(cur ^ 1, (t + 1) * 32);

            short8v a[4], b[4], al[4], bl[4];
#pragma unroll
            for (int m = 0; m < 4; ++m)
                a[m] = *(const short8v*)&Acur[(mw + m * 16 + fr) * 32 + rdsw];
#pragma unroll
            for (int n = 0; n < 4; ++n)
                b[n] = *(const short8v*)&Bcur[(nw + n * 16 + fr) * 32 + rdsw];
#pragma unroll
            for (int m = 0; m < 4; ++m)
                al[m] = *(const short8v*)&Acur[TILE + (mw + m * 16 + fr) * 32 + rdsw];
#pragma unroll
            for (int n = 0; n < 4; ++n)
                bl[n] = *(const short8v*)&Bcur[TILE + (nw + n * 16 + fr) * 32 + rdsw];
#pragma unroll
            for (int m = 0; m < 4; ++m)
#pragma unroll
                for (int n = 0; n < 4; ++n) {
                    acc[m][n] = __builtin_amdgcn_mfma_f32_16x16x32_bf16(a[m],  b[n],  acc[m][n], 0, 0, 0);
                    acc[m][n] = __builtin_amdgcn_mfma_f32_16x16x32_bf16(a[m],  bl[n], acc[m][n], 0, 0, 0);
                    acc[m][n] = __builtin_amdgcn_mfma_f32_16x16x32_bf16(al[m], b[n],  acc[m][n], 0, 0, 0);
                }
            __syncthreads();
        }
    } else {
        // ---- ring-3, counted vmcnt, raw barriers (loads stay in flight) ----
        STAGE_ALL(0, 0);
        STAGE_ALL(1, 32);          // NT >= 2 for all call sites (K >= 512)
        int cur = 0;
        for (int t = 0; t < NT; ++t) {
            if (t + 1 < NT) { asm volatile("s_waitcnt vmcnt(4)" ::: "memory"); }
            else            { asm volatile("s_waitcnt vmcnt(0)" ::: "memory"); }
            __builtin_amdgcn_sched_barrier(0);
            __builtin_amdgcn_s_barrier();
            __builtin_amdgcn_sched_barrier(0);

            const ushort* Acur = lds + cur * 2 * TILE;
            const ushort* Bcur = Acur + TILE;
            short8v a[4], b[4];
#pragma unroll
            for (int m = 0; m < 4; ++m)
                a[m] = *(const short8v*)&Acur[(mw + m * 16 + fr) * 32 + rdsw];
#pragma unroll
            for (int n = 0; n < 4; ++n)
                b[n] = *(const short8v*)&Bcur[(nw + n * 16 + fr) * 32 + rdsw];

            if (t + 2 < NT) {
                int nb = cur + 2; if (nb >= 3) nb -= 3;
                STAGE_ALL(nb, (t + 2) * 32);
            }

            asm volatile("s_waitcnt lgkmcnt(0)" ::: "memory");
            __builtin_amdgcn_sched_barrier(0);
            __builtin_amdgcn_s_setprio(1);
#pragma unroll
            for (int m = 0; m < 4; ++m)
#pragma unroll
                for (int n = 0; n < 4; ++n)
                    acc[m][n] = __builtin_amdgcn_mfma_f32_16x16x32_bf16(a[m], b[n], acc[m][n], 0, 0, 0);
            __builtin_amdgcn_s_setprio(0);

            cur = (cur == 2) ? 0 : cur + 1;
        }
        __syncthreads();   // LDS safe to reuse below
    }
#undef STAGE_ALL
#undef STGB
#undef STG

    // ---- epilogue: D[r][c]: c = lane&15, r = (lane>>4)*4 + q
    const int fc = lane & 15;
    const int fq = (lane >> 4) * 4;

    if (!SPLIT && epi == 1) {
        // LDS-transposed, coalesced row stores + fused bias/exp/rowsum.
        float* T = (float*)lds;                 // [32][136] fp32, 17.4 KB
        const int r  = tid >> 3;                // 0..31
        const int cg = tid & 7;                 // 0..7
#pragma unroll
        for (int c = 0; c < 4; ++c) {
            __syncthreads();
            if ((wave >> 1) == (c >> 1)) {
#pragma unroll
                for (int mm = 0; mm < 2; ++mm) {
                    const int m = (c & 1) * 2 + mm;
                    const int lr = mm * 16 + fq;
#pragma unroll
                    for (int n = 0; n < 4; ++n) {
                        float4v v = acc[m][n];
#pragma unroll
                        for (int q = 0; q < 4; ++q)
                            T[(lr + q) * 136 + nw + n * 16 + fc] = v[q];
                    }
                }
            }
            __syncthreads();
            const int grow = i0 + 32 * c + r;
            float s = 0.f;
            float* po = &Cf[(long)grow * ldc + j0 + cg * 16];
#pragma unroll
            for (int w4 = 0; w4 < 4; ++w4) {
                const int col = cg * 16 + w4 * 4;
                const int gc = j0 + col;
                float vv[4];
#pragma unroll
                for (int q2 = 0; q2 < 4; ++q2) {
                    float x = T[r * 136 + col + q2];
                    if (gc + q2 < Ncols) {
                        x += bias[gc + q2];
                        s += __expf(x);
                    }
                    vv[q2] = x;
                }
                if (gc + 3 < Ncols) {
                    *(float4*)(po + w4 * 4) = make_float4(vv[0], vv[1], vv[2], vv[3]);
                } else {
#pragma unroll
                    for (int q2 = 0; q2 < 4; ++q2)
                        if (gc + q2 < Ncols) po[w4 * 4 + q2] = vv[q2];
                }
            }
            s += __shfl_xor(s, 1);
            s += __shfl_xor(s, 2);
            s += __shfl_xor(s, 4);
            if (cg == 0) atomicAdd(&aux[grow], s);
        }
        return;
    }

    float red[4][4];
#pragma unroll
    for (int m = 0; m < 4; ++m)
#pragma unroll
        for (int q = 0; q < 4; ++q) red[m][q] = 0.f;

#pragma unroll
    for (int n = 0; n < 4; ++n) {
        const int col = j0 + nw + n * 16 + fc;
        if (col >= Ncols) continue;
        const float bc = bias ? bias[col] : 0.f;
        const float wg = (epi == 2) ? Wg[col] : 0.f;
#pragma unroll
        for (int m = 0; m < 4; ++m) {
            const int r0 = i0 + mw + m * 16 + fq;
            float4v v = acc[m][n];
#pragma unroll
            for (int q = 0; q < 4; ++q) {
                float x = v[q] + bc;
                if (epi == 0) {
                    Cf[(long)bz * sC + (long)(r0 + q) * ldc + col] = x;
                } else if (epi == 2) {
                    red[m][q] += tanhf(x) * wg;
                } else {
                    C16[(long)bz * sC + (long)(r0 + q) * ldc + col] = f2bf(x);
                }
            }
        }
    }
    if (epi == 2) {
#pragma unroll
        for (int m = 0; m < 4; ++m)
#pragma unroll
            for (int q = 0; q < 4; ++q) {
                float s = red[m][q];
                s += __shfl_xor(s, 1);
                s += __shfl_xor(s, 2);
                s += __shfl_xor(s, 4);
                s += __shfl_xor(s, 8);
                if (fc == 0)
                    atomicAdd(&aux[i0 + mw + m * 16 + fq + q], s);
            }
    }
}

// ---- masked softmax over M=512, in place; attn[m>=len]=0 --------------------
__global__ void softmax_rows(float* __restrict__ s, const int* __restrict__ msl)
{
    __shared__ float red[256];
    const int row = blockIdx.x;
    const int b   = row / Tt;
    const int len = msl[b];
    float* p = s + (long)row * Mm;
    const int tid = threadIdx.x;

    float v[2], mx = -INFINITY;
#pragma unroll
    for (int q = 0; q < 2; ++q) {
        int m = tid + q * 256;
        v[q] = (m < len) ? p[m] : -INFINITY;
        mx = fmaxf(mx, v[q]);
    }
    red[tid] = mx; __syncthreads();
    for (int off = 128; off > 0; off >>= 1) {
        if (tid < off) red[tid] = fmaxf(red[tid], red[tid + off]);
        __syncthreads();
    }
    mx = red[0]; __syncthreads();

    float e[2], sm = 0.f;
#pragma unroll
    for (int q = 0; q < 2; ++q) {
        int m = tid + q * 256;
        e[q] = (m < len) ? expf(v[q] - mx) : 0.f;
        sm += e[q];
    }
    red[tid] = sm; __syncthreads();
    for (int off = 128; off > 0; off >>= 1) {
        if (tid < off) red[tid] += red[tid + off];
        __syncthreads();
    }
    const float inv = 1.0f / red[0];
#pragma unroll
    for (int q = 0; q < 2; ++q) p[tid + q * 256] = e[q] * inv;
}

// ---- zero rowsum + pgacc ----------------------------------------------------
__global__ void init_zero(float* __restrict__ rowsum, float* __restrict__ pgacc)
{
    int i = blockIdx.x * 256 + threadIdx.x;
    if (i < NN) { rowsum[i] = 0.f; pgacc[i] = 0.f; }
}

// ---- pg = sigmoid(pgacc + bg); linv = log(pg / rowsum) ----------------------
__global__ void linv_pg(const float* __restrict__ pgacc, const float* __restrict__ bg,
                        const float* __restrict__ rowsum,
                        float* __restrict__ pg, float* __restrict__ linv)
{
    int i = blockIdx.x * 256 + threadIdx.x;
    if (i < NN) {
        float p = 1.0f / (1.0f + __expf(-(pgacc[i] + bg[0])));
        pg[i] = p;
        linv[i] = __logf(p / rowsum[i]);
    }
}

// ---- fused: out[row][*] += linv[row]; then copy fix-up on <=512 positions ---
__launch_bounds__(256)
__global__ void shift_fix(float* __restrict__ out, const float* __restrict__ attn,
                          const float* __restrict__ pg, const int* __restrict__ ids,
                          const int* __restrict__ msl, const float* __restrict__ linv)
{
    __shared__ int   ids_s[Mm];
    __shared__ float vals_s[Mm];
    const int row = blockIdx.x;
    const int b   = row / Tt;
    const int len = msl[b];
    const int tid = threadIdx.x;
    const float s = linv[row];
    const float c = 1.0f - pg[row];

    for (int m = tid; m < len; m += 256) {
        ids_s[m]  = ids[(long)b * Mm + m];
        vals_s[m] = attn[(long)row * Mm + m] * c;
    }

    float* p = out + (long)row * Vv;
    const int mis  = (int)(((unsigned)((long)row * Vv)) & 3u);
    const int head = (4 - mis) & 3;
    if (tid < head) p[tid] += s;
    const int nv = (Vv - head) >> 2;
    float4* p4 = (float4*)(p + head);
    for (int i = tid; i < nv; i += 256) {
        float4 v = p4[i];
        v.x += s; v.y += s; v.z += s; v.w += s;
        p4[i] = v;
    }
    const int t = head + nv * 4 + tid;
    if (t < Vv) p[t] += s;

    __syncthreads();

    for (int m = tid; m < len; m += 256) {
        const int id = ids_s[m];
        bool first = true;
        float tot = vals_s[m];
        for (int m2 = 0; m2 < len; ++m2) {
            if (ids_s[m2] == id) {
                if (m2 < m) { first = false; break; }
                if (m2 > m) tot += vals_s[m2];
            }
        }
        if (first) p[id] = __logf(__expf(p[id]) + tot);
    }
}

extern "C" void kernel_launch(void* const* d_in, const int* in_sizes, int n_in,
                              void* d_out, int out_size, void* d_ws, size_t ws_size,
                              hipStream_t stream)
{
    const float* dec = (const float*)d_in[0];
    const float* mem = (const float*)d_in[1];
    const int*   msl = (const int*)d_in[2];
    const int*   ids = (const int*)d_in[3];
    const float* Wc  = (const float*)d_in[4];
    // d_in[5] = b_copy: per-(b,t)-constant shift of scores -> softmax-invariant; skip.
    const float* Wd  = (const float*)d_in[6];
    const float* bd  = (const float*)d_in[7];
    const float* Wg  = (const float*)d_in[8];
    const float* bg  = (const float*)d_in[9];
    const float* Wo  = (const float*)d_in[10];
    const float* bo  = (const float*)d_in[11];

    float* out = (float*)d_out;

    // ---- ws layout (~107 MB) ----
    float* ws     = (float*)d_ws;
    float* attn   = ws;                          // NN*Mm fp32 (survives to shift_fix)
    float* pg     = attn + (size_t)NN * Mm;
    float* linv   = pg + NN;
    float* rowsum = linv + NN;
    float* pgacc  = rowsum + NN;
    ushort* A16   = (ushort*)(pgacc + NN);       // dec_hi  NN*Dd
    ushort* B16   = A16 + (size_t)NN * Dd;       // W_out   Vv*Dd

    // ---- d_out doubles as scratch; everything consumed before logits GEMM ----
    ushort* S      = (ushort*)d_out;
    ushort* dec_lo = S;
    ushort* WcT_hi = dec_lo + (size_t)NN * Dd;
    ushort* WcT_lo = WcT_hi + (size_t)Dd * Dd;
    ushort* mem_hi = WcT_lo + (size_t)Dd * Dd;
    ushort* mem_lo = mem_hi + (size_t)Bb * Mm * Dd;
    ushort* memT16 = mem_lo + (size_t)Bb * Mm * Dd;
    ushort* dp_hi  = memT16 + (size_t)Bb * Mm * Dd;
    ushort* dp_lo  = dp_hi + (size_t)NN * Dd;
    ushort* Wd16   = dp_lo + (size_t)NN * Dd;
    ushort* attn16 = Wd16 + (size_t)Dd * 2 * Dd;
    ushort* ao16   = attn16 + (size_t)NN * Mm;   // attn_out bf16
    float* dec_proj = (float*)(ao16 + (size_t)NN * Dd);

    // 0. init + precision prep
    init_zero<<<DIV_UP(NN,256), 256, 0, stream>>>(rowsum, pgacc);
    split_cast<<<256, 256, 0, stream>>>(dec, A16, dec_lo, (long)NN * Dd / 8);
    split_cast<<<512, 256, 0, stream>>>(mem, mem_hi, mem_lo, (long)Bb * Mm * Dd / 8);
    transpose_split<<<dim3(Dd/32, Dd/32, 1), 256, 0, stream>>>(Wc, WcT_hi, WcT_lo, Dd, Dd);
    transpose_split<<<dim3(Dd/32, Mm/32, Bb), 256, 0, stream>>>(mem, memT16, nullptr, Mm, Dd);
    cast_bf16<<<512, 256, 0, stream>>>(Wd, Wd16, (long)Dd * 2 * Dd / 8);
    cast_bf16<<<2048, 256, 0, stream>>>(Wo, B16, (long)Vv * Dd / 8);

    // 1. dec_proj = dec @ W_copy^T-form (split-bf16, ~fp32 accuracy)
    gemm_mx<true><<<dim3(Dd/128, NN/128, 1), 256, 0, stream>>>(
        A16, dec_lo, WcT_hi, WcT_lo, A16, Dd, Dd, nullptr,
        dec_proj, nullptr, nullptr, nullptr,
        Dd, Dd, Dd, Dd, Dd, 0, 0, 0, 0, 0);
    split_cast<<<256, 256, 0, stream>>>(dec_proj, dp_hi, dp_lo, (long)NN * Dd / 8);

    // 2. scores[b] = dec_proj[b] @ mem[b]^T (split-bf16, batched)
    gemm_mx<true><<<dim3(Mm/128, Tt/128, Bb), 256, 0, stream>>>(
        dp_hi, dp_lo, mem_hi, mem_lo, dp_hi, Dd, Dd, nullptr,
        attn, nullptr, nullptr, nullptr,
        Mm, Dd, Dd, Dd, Mm, (long)Tt*Dd, (long)Mm*Dd, (long)Tt*Mm, 0, 0);

    // 3. masked softmax (fp32)
    softmax_rows<<<NN, 256, 0, stream>>>(attn, msl);
    cast_bf16<<<128, 256, 0, stream>>>(attn, attn16, (long)NN * Mm / 8);

    // 4. attn_out16[b] = attn[b] @ mem[b] (bf16; feeds only p_gen)
    gemm_mx<false><<<dim3(Dd/128, Tt/128, Bb), 256, 0, stream>>>(
        attn16, attn16, memT16, memT16, attn16, Mm, Mm, nullptr,
        nullptr, ao16, nullptr, nullptr,
        Dd, Mm, Mm, Mm, Dd, (long)Tt*Mm, (long)Dd*Mm, (long)Tt*Dd, 4, 0);

    // 5+6. pgacc[row] = sum_d tanh(([dec|attn_out] @ Wd^T + bd)[row,d]) * Wg[d]
    gemm_mx<false><<<dim3(Dd/128, NN/128, 1), 256, 0, stream>>>(
        A16, A16, Wd16, Wd16, ao16, Dd, Dd, bd,
        nullptr, nullptr, pgacc, Wg,
        Dd, 2*Dd, Dd, 2*Dd, 0, 0, 0, 0, 2, 0);

    // 7. logits = dec @ W_out^T + b_out -> out; rowsum += sum(exp). XCD-swizzled,
    //    ring-3 counted-vmcnt loop, coalesced LDS-transpose epilogue.
    gemm_mx<false><<<8 * 8 * DIV_UP(DIV_UP(Vv,128), 8), 256, 0, stream>>>(
        A16, A16, B16, B16, A16, Dd, Dd, bo,
        out, nullptr, rowsum, nullptr,
        Vv, Dd, Dd, Dd, Vv, 0, 0, 0, 1, DIV_UP(Vv,128));

    // 8. pg + linv
    linv_pg<<<DIV_UP(NN,256), 256, 0, stream>>>(pgacc, bg, rowsum, pg, linv);

    // 9. fused shift + copy fix-up
    shift_fix<<<NN, 256, 0, stream>>>(out, attn, pg, ids, msl, linv);
}

// Round 8
// 720.706 us; speedup vs baseline: 1.0146x; 1.0146x over previous
//
#include <hip/hip_runtime.h>
#include <math.h>

#define DIV_UP(a,b) (((a)+(b)-1)/(b))

static constexpr int Bb = 4, Tt = 256, Mm = 512, Dd = 1024, Vv = 50257;
static constexpr int NN = Bb * Tt;   // 1024 flattened (b,t) rows

typedef __attribute__((ext_vector_type(8))) short short8v;
typedef __attribute__((ext_vector_type(4))) float float4v;
typedef unsigned short ushort;

// fp32 -> bf16 RNE (bit trick, branchless)
static __device__ __forceinline__ ushort f2bf(float f) {
    unsigned u = __float_as_uint(f);
    u += 0x7FFFu + ((u >> 16) & 1u);
    return (ushort)(u >> 16);
}
static __device__ __forceinline__ float bf2f(ushort h) {
    return __uint_as_float(((unsigned)h) << 16);
}

// async 16B global -> LDS (wave-uniform base + lane*16 dest)
static __device__ __forceinline__ void gload16(const void* g, void* l) {
    __builtin_amdgcn_global_load_lds(
        (const __attribute__((address_space(1))) unsigned int*)g,
        (__attribute__((address_space(3))) unsigned int*)l, 16, 0, 0);
}

// ---- fp32 -> bf16 cast, 8/thread --------------------------------------------
__launch_bounds__(256)
__global__ void cast_bf16(const float* __restrict__ src, ushort* __restrict__ dst, long n8)
{
    for (long i = blockIdx.x * 256 + threadIdx.x; i < n8; i += (long)gridDim.x * 256) {
        const float4 v0 = *(const float4*)&src[i * 8];
        const float4 v1 = *(const float4*)&src[i * 8 + 4];
        short8v t;
        t[0]=f2bf(v0.x); t[1]=f2bf(v0.y); t[2]=f2bf(v0.z); t[3]=f2bf(v0.w);
        t[4]=f2bf(v1.x); t[5]=f2bf(v1.y); t[6]=f2bf(v1.z); t[7]=f2bf(v1.w);
        *(short8v*)&dst[i * 8] = t;
    }
}

// ---- fp32 -> (hi, lo) bf16 split, 8/thread ----------------------------------
__launch_bounds__(256)
__global__ void split_cast(const float* __restrict__ src, ushort* __restrict__ hi,
                           ushort* __restrict__ lo, long n8)
{
    for (long i = blockIdx.x * 256 + threadIdx.x; i < n8; i += (long)gridDim.x * 256) {
        short8v th, tl;
#pragma unroll
        for (int q = 0; q < 8; ++q) {
            float v = src[i * 8 + q];
            ushort h = f2bf(v);
            th[q] = h;
            tl[q] = f2bf(v - bf2f(h));
        }
        *(short8v*)&hi[i * 8] = th;
        *(short8v*)&lo[i * 8] = tl;
    }
}

// ---- batched transpose: in[b] R x C fp32 -> out[b] C x R bf16 (hi, opt lo) --
__launch_bounds__(256)
__global__ void transpose_split(const float* __restrict__ in, ushort* __restrict__ oh,
                                ushort* __restrict__ ol, int R, int C)
{
    __shared__ float t[32][33];
    const int bz = blockIdx.z;
    in += (long)bz * R * C;
    oh += (long)bz * R * C;
    if (ol) ol += (long)bz * R * C;
    const int tx = threadIdx.x & 31, ty = threadIdx.x >> 5;
    const int r0 = blockIdx.y * 32, c0 = blockIdx.x * 32;
#pragma unroll
    for (int k = 0; k < 4; ++k)
        t[ty + k * 8][tx] = in[(long)(r0 + ty + k * 8) * C + c0 + tx];
    __syncthreads();
#pragma unroll
    for (int k = 0; k < 4; ++k) {
        float v = t[tx][ty + k * 8];
        ushort h = f2bf(v);
        long o = (long)(c0 + ty + k * 8) * R + r0 + tx;
        oh[o] = h;
        if (ol) ol[o] = f2bf(v - bf2f(h));
    }
}

// ---------------------------------------------------------------------------
// Unified bf16 MFMA GEMM (NT): C[i,j] = sum_k A[i,k]*B[j,k]
// SPLIT: 3-pass split-bf16 (Ah*Bh + Ah*Bl + Al*Bh), proven 2-buffer drain loop.
// non-SPLIT: ring-3 LDS, counted vmcnt BEFORE barrier (per-wave drain ->
//   barrier publishes all waves' tile quarters), single anti-hoist fence,
//   compiler-managed lgkmcnt, no setprio (null pre-8-phase, m190).
// Source addrs pre-swizzled so ds_read_b128 frag reads are bank-balanced.
// epi: 0 = fp32 C; 1 = fp32 C + bias + rowsum[i] += sum_j exp(x), via
//      LDS-transposed coalesced row stores; 2 = pgacc[i] += sum tanh(x+b)*Wg;
//      4 = bf16 C write.
// xcd_jtiles > 0: flat-grid XCD swizzle (8 M-tiles fast per XCD chunk).
// ---------------------------------------------------------------------------
template<bool SPLIT>
__launch_bounds__(256)
__global__ void gemm_mx(const ushort* __restrict__ Ah, const ushort* __restrict__ Al,
                        const ushort* __restrict__ Bh, const ushort* __restrict__ Bl,
                        const ushort* __restrict__ A2, int ksplit, int lda2,
                        const float* __restrict__ bias,
                        float* __restrict__ Cf, ushort* __restrict__ C16,
                        float* __restrict__ aux, const float* __restrict__ Wg,
                        int Ncols, int K, int lda, int ldb, int ldc,
                        long sA, long sB, long sC, int epi, int xcd_jtiles)
{
    constexpr int TILE = 4096;   // ushorts per 128x32 bf16 tile (8 KB)
    // SPLIT: 2 buffers x 4 tiles (64 KB); non-split: 3-ring x 2 tiles (48 KB)
    __shared__ __align__(16) ushort lds[SPLIT ? 8 * TILE : 6 * TILE];

    int mt, jt, bz;
    if (xcd_jtiles > 0) {
        const int id = blockIdx.x;
        const int s = id >> 3;
        jt = (id & 7) * ((xcd_jtiles + 7) >> 3) + (s >> 3);
        mt = s & 7;
        bz = 0;
        if (jt >= xcd_jtiles) return;
    } else { jt = blockIdx.x; mt = blockIdx.y; bz = blockIdx.z; }

    const int tid  = threadIdx.x;
    const int lane = tid & 63;
    const int wave = tid >> 6;
    const int mw = (wave >> 1) * 64, nw = (wave & 1) * 64;
    const int i0 = mt * 128, j0 = jt * 128;

    const int srow = tid >> 2;
    const int soff = ((tid & 3) ^ ((srow >> 1) & 3)) * 8;   // swizzled source slot

    const long Ab = (long)bz * sA;
    const long Bz = (long)bz * sB;
    const long ar0 = i0 + srow, ar1 = i0 + 64 + srow;
    long br0 = j0 + srow;      if (br0 > Ncols - 1) br0 = Ncols - 1;
    long br1 = j0 + 64 + srow; if (br1 > Ncols - 1) br1 = Ncols - 1;

    const int NT = K >> 5;

    float4v acc[4][4];
#pragma unroll
    for (int m = 0; m < 4; ++m)
#pragma unroll
        for (int n = 0; n < 4; ++n) acc[m][n] = (float4v){0.f, 0.f, 0.f, 0.f};

#define STG(dst, src, kc) \
    gload16(&(src)[ar0 * lA + (kc) + soff], (dst) + tid * 8); \
    gload16(&(src)[ar1 * lA + (kc) + soff], (dst) + 2048 + tid * 8);
#define STGB(dst, src, kc) \
    gload16(&(src)[br0 * ldb + (kc) + soff], (dst) + tid * 8); \
    gload16(&(src)[br1 * ldb + (kc) + soff], (dst) + 2048 + tid * 8);

#define STAGE_ALL(buf, kc)                                                     \
    {                                                                          \
        const bool sec = (kc) >= ksplit;                                       \
        const int  kk  = sec ? (kc) - ksplit : (kc);                           \
        const int  lA  = sec ? lda2 : lda;                                     \
        constexpr int BS = SPLIT ? 4 * TILE : 2 * TILE;                        \
        ushort* dA = lds + (buf) * BS;                                         \
        if (SPLIT) {                                                           \
            STG(dA, Ah + Ab, kk);                                              \
            STG(dA + TILE, Al + Ab, kk);                                       \
            STGB(dA + 2 * TILE, Bh + Bz, kc);                                  \
            STGB(dA + 3 * TILE, Bl + Bz, kc);                                  \
        } else {                                                               \
            const ushort* As = sec ? A2 : Ah;                                  \
            STG(dA, As + Ab, kk);                                              \
            STGB(dA + TILE, Bh + Bz, kc);                                      \
        }                                                                      \
    }

    const int fr = lane & 15;
    const int rdsw = (((lane >> 4) ^ ((fr >> 1) & 3))) * 8;  // swizzled read slot

    if constexpr (SPLIT) {
        // ---- proven 2-buffer drain loop ----
        STAGE_ALL(0, 0);
        __syncthreads();
        for (int t = 0; t < NT; ++t) {
            const int cur = t & 1;
            const ushort* Acur = lds + cur * 4 * TILE;
            const ushort* Bcur = Acur + 2 * TILE;

            if (t + 1 < NT) STAGE_ALL(cur ^ 1, (t + 1) * 32);

            short8v a[4], b[4], al[4], bl[4];
#pragma unroll
            for (int m = 0; m < 4; ++m)
                a[m] = *(const short8v*)&Acur[(mw + m * 16 + fr) * 32 + rdsw];
#pragma unroll
            for (int n = 0; n < 4; ++n)
                b[n] = *(const short8v*)&Bcur[(nw + n * 16 + fr) * 32 + rdsw];
#pragma unroll
            for (int m = 0; m < 4; ++m)
                al[m] = *(const short8v*)&Acur[TILE + (mw + m * 16 + fr) * 32 + rdsw];
#pragma unroll
            for (int n = 0; n < 4; ++n)
                bl[n] = *(const short8v*)&Bcur[TILE + (nw + n * 16 + fr) * 32 + rdsw];
#pragma unroll
            for (int m = 0; m < 4; ++m)
#pragma unroll
                for (int n = 0; n < 4; ++n) {
                    acc[m][n] = __builtin_amdgcn_mfma_f32_16x16x32_bf16(a[m],  b[n],  acc[m][n], 0, 0, 0);
                    acc[m][n] = __builtin_amdgcn_mfma_f32_16x16x32_bf16(a[m],  bl[n], acc[m][n], 0, 0, 0);
                    acc[m][n] = __builtin_amdgcn_mfma_f32_16x16x32_bf16(al[m], b[n],  acc[m][n], 0, 0, 0);
                }
            __syncthreads();
        }
    } else {
        // ---- ring-3, counted vmcnt, minimal fencing ----
        STAGE_ALL(0, 0);
        STAGE_ALL(1, 32);          // NT >= 2 for all call sites (K >= 512)
        int cur = 0;
        for (int t = 0; t < NT; ++t) {
            // per-wave drain of THIS tile's loads, then barrier publishes all
            // waves' quarters. Counted N=4 keeps next tile's loads in flight.
            if (t + 1 < NT) { asm volatile("s_waitcnt vmcnt(4)" ::: "memory"); }
            else            { asm volatile("s_waitcnt vmcnt(0)" ::: "memory"); }
            __builtin_amdgcn_s_barrier();
            __builtin_amdgcn_sched_barrier(0);   // keep ds_reads below barrier

            const ushort* Acur = lds + cur * 2 * TILE;
            const ushort* Bcur = Acur + TILE;
            short8v a[4], b[4];
#pragma unroll
            for (int m = 0; m < 4; ++m)
                a[m] = *(const short8v*)&Acur[(mw + m * 16 + fr) * 32 + rdsw];
#pragma unroll
            for (int n = 0; n < 4; ++n)
                b[n] = *(const short8v*)&Bcur[(nw + n * 16 + fr) * 32 + rdsw];

            if (t + 2 < NT) {
                int nb = cur + 2; if (nb >= 3) nb -= 3;
                STAGE_ALL(nb, (t + 2) * 32);
            }

            // compiler inserts lgkmcnt waits for ds_read -> MFMA deps
#pragma unroll
            for (int m = 0; m < 4; ++m)
#pragma unroll
                for (int n = 0; n < 4; ++n)
                    acc[m][n] = __builtin_amdgcn_mfma_f32_16x16x32_bf16(a[m], b[n], acc[m][n], 0, 0, 0);

            cur = (cur == 2) ? 0 : cur + 1;
        }
        __syncthreads();   // LDS safe to reuse below
    }
#undef STAGE_ALL
#undef STGB
#undef STG

    // ---- epilogue: D[r][c]: c = lane&15, r = (lane>>4)*4 + q
    const int fc = lane & 15;
    const int fq = (lane >> 4) * 4;

    if (!SPLIT && epi == 1) {
        // LDS-transposed, coalesced row stores + fused bias/exp/rowsum.
        // Stride 132: write groups 2-way (free); read quads 4-way (vs 8 @136).
        constexpr int TS = 132;
        float* T = (float*)lds;                 // [32][132] fp32, 16.9 KB
        const int r  = tid >> 3;                // 0..31
        const int cg = tid & 7;                 // 0..7
#pragma unroll
        for (int c = 0; c < 4; ++c) {
            __syncthreads();
            if ((wave >> 1) == (c >> 1)) {
#pragma unroll
                for (int mm = 0; mm < 2; ++mm) {
                    const int m = (c & 1) * 2 + mm;
                    const int lr = mm * 16 + fq;
#pragma unroll
                    for (int n = 0; n < 4; ++n) {
                        float4v v = acc[m][n];
#pragma unroll
                        for (int q = 0; q < 4; ++q)
                            T[(lr + q) * TS + nw + n * 16 + fc] = v[q];
                    }
                }
            }
            __syncthreads();
            const int grow = i0 + 32 * c + r;
            float s = 0.f;
            float* po = &Cf[(long)grow * ldc + j0 + cg * 16];
#pragma unroll
            for (int w4 = 0; w4 < 4; ++w4) {
                const int col = cg * 16 + w4 * 4;
                const int gc = j0 + col;
                float vv[4];
#pragma unroll
                for (int q2 = 0; q2 < 4; ++q2) {
                    float x = T[r * TS + col + q2];
                    if (gc + q2 < Ncols) {
                        x += bias[gc + q2];
                        s += __expf(x);
                    }
                    vv[q2] = x;
                }
                if (gc + 3 < Ncols) {
                    *(float4*)(po + w4 * 4) = make_float4(vv[0], vv[1], vv[2], vv[3]);
                } else {
#pragma unroll
                    for (int q2 = 0; q2 < 4; ++q2)
                        if (gc + q2 < Ncols) po[w4 * 4 + q2] = vv[q2];
                }
            }
            s += __shfl_xor(s, 1);
            s += __shfl_xor(s, 2);
            s += __shfl_xor(s, 4);
            if (cg == 0) atomicAdd(&aux[grow], s);
        }
        return;
    }

    float red[4][4];
#pragma unroll
    for (int m = 0; m < 4; ++m)
#pragma unroll
        for (int q = 0; q < 4; ++q) red[m][q] = 0.f;

#pragma unroll
    for (int n = 0; n < 4; ++n) {
        const int col = j0 + nw + n * 16 + fc;
        if (col >= Ncols) continue;
        const float bc = bias ? bias[col] : 0.f;
        const float wg = (epi == 2) ? Wg[col] : 0.f;
#pragma unroll
        for (int m = 0; m < 4; ++m) {
            const int r0 = i0 + mw + m * 16 + fq;
            float4v v = acc[m][n];
#pragma unroll
            for (int q = 0; q < 4; ++q) {
                float x = v[q] + bc;
                if (epi == 0) {
                    Cf[(long)bz * sC + (long)(r0 + q) * ldc + col] = x;
                } else if (epi == 2) {
                    red[m][q] += tanhf(x) * wg;
                } else {
                    C16[(long)bz * sC + (long)(r0 + q) * ldc + col] = f2bf(x);
                }
            }
        }
    }
    if (epi == 2) {
#pragma unroll
        for (int m = 0; m < 4; ++m)
#pragma unroll
            for (int q = 0; q < 4; ++q) {
                float s = red[m][q];
                s += __shfl_xor(s, 1);
                s += __shfl_xor(s, 2);
                s += __shfl_xor(s, 4);
                s += __shfl_xor(s, 8);
                if (fc == 0)
                    atomicAdd(&aux[i0 + mw + m * 16 + fq + q], s);
            }
    }
}

// ---- masked softmax over M=512, in place; also writes bf16 copy and zeroes
// ---- this row's rowsum/pgacc accumulators (runs before both GEMM consumers).
__global__ void softmax_rows(float* __restrict__ s, ushort* __restrict__ s16,
                             const int* __restrict__ msl,
                             float* __restrict__ rowsum, float* __restrict__ pgacc)
{
    __shared__ float red[256];
    const int row = blockIdx.x;
    const int b   = row / Tt;
    const int len = msl[b];
    float* p = s + (long)row * Mm;
    ushort* p16 = s16 + (long)row * Mm;
    const int tid = threadIdx.x;

    if (tid == 0) { rowsum[row] = 0.f; pgacc[row] = 0.f; }

    float v[2], mx = -INFINITY;
#pragma unroll
    for (int q = 0; q < 2; ++q) {
        int m = tid + q * 256;
        v[q] = (m < len) ? p[m] : -INFINITY;
        mx = fmaxf(mx, v[q]);
    }
    red[tid] = mx; __syncthreads();
    for (int off = 128; off > 0; off >>= 1) {
        if (tid < off) red[tid] = fmaxf(red[tid], red[tid + off]);
        __syncthreads();
    }
    mx = red[0]; __syncthreads();

    float e[2], sm = 0.f;
#pragma unroll
    for (int q = 0; q < 2; ++q) {
        int m = tid + q * 256;
        e[q] = (m < len) ? expf(v[q] - mx) : 0.f;
        sm += e[q];
    }
    red[tid] = sm; __syncthreads();
    for (int off = 128; off > 0; off >>= 1) {
        if (tid < off) red[tid] += red[tid + off];
        __syncthreads();
    }
    const float inv = 1.0f / red[0];
#pragma unroll
    for (int q = 0; q < 2; ++q) {
        float a = e[q] * inv;
        p[tid + q * 256] = a;
        p16[tid + q * 256] = f2bf(a);
    }
}

// ---- fused: pg/linv from per-row scalars; out[row][*] += linv; copy fix-up --
__launch_bounds__(256)
__global__ void shift_fix(float* __restrict__ out, const float* __restrict__ attn,
                          const float* __restrict__ pgacc, const float* __restrict__ bg,
                          const float* __restrict__ rowsum,
                          const int* __restrict__ ids, const int* __restrict__ msl)
{
    __shared__ int   ids_s[Mm];
    __shared__ float vals_s[Mm];
    const int row = blockIdx.x;
    const int b   = row / Tt;
    const int len = msl[b];
    const int tid = threadIdx.x;

    const float pgl = 1.0f / (1.0f + __expf(-(pgacc[row] + bg[0])));
    const float s = __logf(pgl / rowsum[row]);
    const float c = 1.0f - pgl;

    for (int m = tid; m < len; m += 256) {
        ids_s[m]  = ids[(long)b * Mm + m];
        vals_s[m] = attn[(long)row * Mm + m] * c;
    }

    float* p = out + (long)row * Vv;
    const int mis  = (int)(((unsigned)((long)row * Vv)) & 3u);
    const int head = (4 - mis) & 3;
    if (tid < head) p[tid] += s;
    const int nv = (Vv - head) >> 2;
    float4* p4 = (float4*)(p + head);
    for (int i = tid; i < nv; i += 256) {
        float4 v = p4[i];
        v.x += s; v.y += s; v.z += s; v.w += s;
        p4[i] = v;
    }
    const int t = head + nv * 4 + tid;
    if (t < Vv) p[t] += s;

    __syncthreads();

    for (int m = tid; m < len; m += 256) {
        const int id = ids_s[m];
        bool first = true;
        float tot = vals_s[m];
        for (int m2 = 0; m2 < len; ++m2) {
            if (ids_s[m2] == id) {
                if (m2 < m) { first = false; break; }
                if (m2 > m) tot += vals_s[m2];
            }
        }
        if (first) p[id] = __logf(__expf(p[id]) + tot);
    }
}

extern "C" void kernel_launch(void* const* d_in, const int* in_sizes, int n_in,
                              void* d_out, int out_size, void* d_ws, size_t ws_size,
                              hipStream_t stream)
{
    const float* dec = (const float*)d_in[0];
    const float* mem = (const float*)d_in[1];
    const int*   msl = (const int*)d_in[2];
    const int*   ids = (const int*)d_in[3];
    const float* Wc  = (const float*)d_in[4];
    // d_in[5] = b_copy: per-(b,t)-constant shift of scores -> softmax-invariant; skip.
    const float* Wd  = (const float*)d_in[6];
    const float* bd  = (const float*)d_in[7];
    const float* Wg  = (const float*)d_in[8];
    const float* bg  = (const float*)d_in[9];
    const float* Wo  = (const float*)d_in[10];
    const float* bo  = (const float*)d_in[11];

    float* out = (float*)d_out;

    // ---- ws layout (~107 MB) ----
    float* ws     = (float*)d_ws;
    float* attn   = ws;                          // NN*Mm fp32 (survives to shift_fix)
    float* rowsum = attn + (size_t)NN * Mm;
    float* pgacc  = rowsum + NN;
    ushort* A16   = (ushort*)(pgacc + NN);       // dec_hi  NN*Dd
    ushort* B16   = A16 + (size_t)NN * Dd;       // W_out   Vv*Dd

    // ---- d_out doubles as scratch; everything consumed before logits GEMM ----
    ushort* S      = (ushort*)d_out;
    ushort* dec_lo = S;
    ushort* WcT_hi = dec_lo + (size_t)NN * Dd;
    ushort* WcT_lo = WcT_hi + (size_t)Dd * Dd;
    ushort* mem_hi = WcT_lo + (size_t)Dd * Dd;
    ushort* mem_lo = mem_hi + (size_t)Bb * Mm * Dd;
    ushort* memT16 = mem_lo + (size_t)Bb * Mm * Dd;
    ushort* dp_hi  = memT16 + (size_t)Bb * Mm * Dd;
    ushort* dp_lo  = dp_hi + (size_t)NN * Dd;
    ushort* Wd16   = dp_lo + (size_t)NN * Dd;
    ushort* attn16 = Wd16 + (size_t)Dd * 2 * Dd;
    ushort* ao16   = attn16 + (size_t)NN * Mm;   // attn_out bf16
    float* dec_proj = (float*)(ao16 + (size_t)NN * Dd);

    // 0. precision prep
    split_cast<<<256, 256, 0, stream>>>(dec, A16, dec_lo, (long)NN * Dd / 8);
    split_cast<<<512, 256, 0, stream>>>(mem, mem_hi, mem_lo, (long)Bb * Mm * Dd / 8);
    transpose_split<<<dim3(Dd/32, Dd/32, 1), 256, 0, stream>>>(Wc, WcT_hi, WcT_lo, Dd, Dd);
    transpose_split<<<dim3(Dd/32, Mm/32, Bb), 256, 0, stream>>>(mem, memT16, nullptr, Mm, Dd);
    cast_bf16<<<512, 256, 0, stream>>>(Wd, Wd16, (long)Dd * 2 * Dd / 8);
    cast_bf16<<<2048, 256, 0, stream>>>(Wo, B16, (long)Vv * Dd / 8);

    // 1. dec_proj = dec @ W_copy^T-form (split-bf16, ~fp32 accuracy)
    gemm_mx<true><<<dim3(Dd/128, NN/128, 1), 256, 0, stream>>>(
        A16, dec_lo, WcT_hi, WcT_lo, A16, Dd, Dd, nullptr,
        dec_proj, nullptr, nullptr, nullptr,
        Dd, Dd, Dd, Dd, Dd, 0, 0, 0, 0, 0);
    split_cast<<<256, 256, 0, stream>>>(dec_proj, dp_hi, dp_lo, (long)NN * Dd / 8);

    // 2. scores[b] = dec_proj[b] @ mem[b]^T (split-bf16, batched)
    gemm_mx<true><<<dim3(Mm/128, Tt/128, Bb), 256, 0, stream>>>(
        dp_hi, dp_lo, mem_hi, mem_lo, dp_hi, Dd, Dd, nullptr,
        attn, nullptr, nullptr, nullptr,
        Mm, Dd, Dd, Dd, Mm, (long)Tt*Dd, (long)Mm*Dd, (long)Tt*Mm, 0, 0);

    // 3. masked softmax (fp32 + bf16 outputs; zeroes rowsum/pgacc)
    softmax_rows<<<NN, 256, 0, stream>>>(attn, attn16, msl, rowsum, pgacc);

    // 4. attn_out16[b] = attn[b] @ mem[b] (bf16; feeds only p_gen)
    gemm_mx<false><<<dim3(Dd/128, Tt/128, Bb), 256, 0, stream>>>(
        attn16, attn16, memT16, memT16, attn16, Mm, Mm, nullptr,
        nullptr, ao16, nullptr, nullptr,
        Dd, Mm, Mm, Mm, Dd, (long)Tt*Mm, (long)Dd*Mm, (long)Tt*Dd, 4, 0);

    // 5+6. pgacc[row] = sum_d tanh(([dec|attn_out] @ Wd^T + bd)[row,d]) * Wg[d]
    gemm_mx<false><<<dim3(Dd/128, NN/128, 1), 256, 0, stream>>>(
        A16, A16, Wd16, Wd16, ao16, Dd, Dd, bd,
        nullptr, nullptr, pgacc, Wg,
        Dd, 2*Dd, Dd, 2*Dd, 0, 0, 0, 0, 2, 0);

    // 7. logits = dec @ W_out^T + b_out -> out; rowsum += sum(exp). XCD-swizzled,
    //    ring-3 counted-vmcnt loop, coalesced LDS-transpose epilogue.
    gemm_mx<false><<<8 * 8 * DIV_UP(DIV_UP(Vv,128), 8), 256, 0, stream>>>(
        A16, A16, B16, B16, A16, Dd, Dd, bo,
        out, nullptr, rowsum, nullptr,
        Vv, Dd, Dd, Dd, Vv, 0, 0, 0, 1, DIV_UP(Vv,128));

    // 8. fused pg/linv + shift + copy fix-up
    shift_fix<<<NN, 256, 0, stream>>>(out, attn, pgacc, bg, rowsum, ids, msl);
}

// Round 10
// 686.849 us; speedup vs baseline: 1.0646x; 1.0493x over previous
//
#include <hip/hip_runtime.h>
#include <math.h>

#define DIV_UP(a,b) (((a)+(b)-1)/(b))

static constexpr int Bb = 4, Tt = 256, Mm = 512, Dd = 1024, Vv = 50257;
static constexpr int NN = Bb * Tt;   // 1024 flattened (b,t) rows

typedef __attribute__((ext_vector_type(8))) short short8v;
typedef __attribute__((ext_vector_type(4))) float float4v;
typedef unsigned short ushort;

// fp32 -> bf16 RNE (bit trick, branchless)
static __device__ __forceinline__ ushort f2bf(float f) {
    unsigned u = __float_as_uint(f);
    u += 0x7FFFu + ((u >> 16) & 1u);
    return (ushort)(u >> 16);
}
static __device__ __forceinline__ float bf2f(ushort h) {
    return __uint_as_float(((unsigned)h) << 16);
}

// async 16B global -> LDS (wave-uniform base + lane*16 dest)
static __device__ __forceinline__ void gload16(const void* g, void* l) {
    __builtin_amdgcn_global_load_lds(
        (const __attribute__((address_space(1))) unsigned int*)g,
        (__attribute__((address_space(3))) unsigned int*)l, 16, 0, 0);
}

// ---- fp32 -> bf16 cast, 8/thread --------------------------------------------
__launch_bounds__(256)
__global__ void cast_bf16(const float* __restrict__ src, ushort* __restrict__ dst, long n8)
{
    for (long i = blockIdx.x * 256 + threadIdx.x; i < n8; i += (long)gridDim.x * 256) {
        const float4 v0 = *(const float4*)&src[i * 8];
        const float4 v1 = *(const float4*)&src[i * 8 + 4];
        short8v t;
        t[0]=f2bf(v0.x); t[1]=f2bf(v0.y); t[2]=f2bf(v0.z); t[3]=f2bf(v0.w);
        t[4]=f2bf(v1.x); t[5]=f2bf(v1.y); t[6]=f2bf(v1.z); t[7]=f2bf(v1.w);
        *(short8v*)&dst[i * 8] = t;
    }
}

// ---- fp32 -> (hi, lo) bf16 split, 8/thread ----------------------------------
__launch_bounds__(256)
__global__ void split_cast(const float* __restrict__ src, ushort* __restrict__ hi,
                           ushort* __restrict__ lo, long n8)
{
    for (long i = blockIdx.x * 256 + threadIdx.x; i < n8; i += (long)gridDim.x * 256) {
        short8v th, tl;
#pragma unroll
        for (int q = 0; q < 8; ++q) {
            float v = src[i * 8 + q];
            ushort h = f2bf(v);
            th[q] = h;
            tl[q] = f2bf(v - bf2f(h));
        }
        *(short8v*)&hi[i * 8] = th;
        *(short8v*)&lo[i * 8] = tl;
    }
}

// ---- batched transpose: in[b] R x C fp32 -> out[b] C x R bf16 (hi, opt lo) --
__launch_bounds__(256)
__global__ void transpose_split(const float* __restrict__ in, ushort* __restrict__ oh,
                                ushort* __restrict__ ol, int R, int C)
{
    __shared__ float t[32][33];
    const int bz = blockIdx.z;
    in += (long)bz * R * C;
    oh += (long)bz * R * C;
    if (ol) ol += (long)bz * R * C;
    const int tx = threadIdx.x & 31, ty = threadIdx.x >> 5;
    const int r0 = blockIdx.y * 32, c0 = blockIdx.x * 32;
#pragma unroll
    for (int k = 0; k < 4; ++k)
        t[ty + k * 8][tx] = in[(long)(r0 + ty + k * 8) * C + c0 + tx];
    __syncthreads();
#pragma unroll
    for (int k = 0; k < 4; ++k) {
        float v = t[tx][ty + k * 8];
        ushort h = f2bf(v);
        long o = (long)(c0 + ty + k * 8) * R + r0 + tx;
        oh[o] = h;
        if (ol) ol[o] = f2bf(v - bf2f(h));
    }
}

// ---------------------------------------------------------------------------
// Unified bf16 MFMA GEMM (NT): C[i,j] = sum_k A[i,k]*B[j,k]
// SPLIT: 3-pass split-bf16 (Ah*Bh + Ah*Bl + Al*Bh), BK=32, 2-buffer drain loop.
// non-SPLIT: BK=64 2-buffer drain loop — doubles MFMA work per vmcnt-drain
//   (the proven-structure stall amortizer; ring/counted variants were null).
//   8-slot XOR swizzle (slot ^= row&7) on pre-swizzled source + ds_read addr.
// epi: 0 = fp32 C; 1 = fp32 C + bias + rowsum[i] += sum_j exp(x), via
//      LDS-transposed coalesced row stores; 2 = pgacc[i] += sum tanh(x+b)*Wg;
//      4 = bf16 C write.
// xcd_jtiles > 0: flat-grid XCD swizzle (8 M-tiles fast per XCD chunk).
// ---------------------------------------------------------------------------
template<bool SPLIT>
__launch_bounds__(256)
__global__ void gemm_mx(const ushort* __restrict__ Ah, const ushort* __restrict__ Al,
                        const ushort* __restrict__ Bh, const ushort* __restrict__ Bl,
                        const ushort* __restrict__ A2, int ksplit, int lda2,
                        const float* __restrict__ bias,
                        float* __restrict__ Cf, ushort* __restrict__ C16,
                        float* __restrict__ aux, const float* __restrict__ Wg,
                        int Ncols, int K, int lda, int ldb, int ldc,
                        long sA, long sB, long sC, int epi, int xcd_jtiles)
{
    constexpr int TILE   = 4096;   // 128x32 bf16 tile (8 KB), SPLIT path
    constexpr int TILE64 = 8192;   // 128x64 bf16 tile (16 KB), non-SPLIT path
    __shared__ __align__(16) ushort lds[32768];   // 64 KB both paths

    int mt, jt, bz;
    if (xcd_jtiles > 0) {
        const int id = blockIdx.x;
        const int s = id >> 3;
        jt = (id & 7) * ((xcd_jtiles + 7) >> 3) + (s >> 3);
        mt = s & 7;
        bz = 0;
        if (jt >= xcd_jtiles) return;
    } else { jt = blockIdx.x; mt = blockIdx.y; bz = blockIdx.z; }

    const int tid  = threadIdx.x;
    const int lane = tid & 63;
    const int wave = tid >> 6;
    const int mw = (wave >> 1) * 64, nw = (wave & 1) * 64;
    const int i0 = mt * 128, j0 = jt * 128;

    const long Ab = (long)bz * sA;
    const long Bz = (long)bz * sB;
    const int fr = lane & 15;

    float4v acc[4][4];
#pragma unroll
    for (int m = 0; m < 4; ++m)
#pragma unroll
        for (int n = 0; n < 4; ++n) acc[m][n] = (float4v){0.f, 0.f, 0.f, 0.f};

    if constexpr (SPLIT) {
        // ---- BK=32, 4-slot source swizzle, proven 2-buffer drain loop ----
        const int srow = tid >> 2;
        const int soff = ((tid & 3) ^ ((srow >> 1) & 3)) * 8;
        const long ar0 = i0 + srow, ar1 = i0 + 64 + srow;
        long br0 = j0 + srow;      if (br0 > Ncols - 1) br0 = Ncols - 1;
        long br1 = j0 + 64 + srow; if (br1 > Ncols - 1) br1 = Ncols - 1;
        const int NT = K >> 5;

#define STG(dst, src, kc) \
        gload16(&(src)[ar0 * lda + (kc) + soff], (dst) + tid * 8); \
        gload16(&(src)[ar1 * lda + (kc) + soff], (dst) + 2048 + tid * 8);
#define STGB(dst, src, kc) \
        gload16(&(src)[br0 * ldb + (kc) + soff], (dst) + tid * 8); \
        gload16(&(src)[br1 * ldb + (kc) + soff], (dst) + 2048 + tid * 8);
#define STAGE_S(buf, kc)                                                       \
        {                                                                      \
            ushort* dA = lds + (buf) * 4 * TILE;                               \
            STG(dA, Ah + Ab, kc);                                              \
            STG(dA + TILE, Al + Ab, kc);                                       \
            STGB(dA + 2 * TILE, Bh + Bz, kc);                                  \
            STGB(dA + 3 * TILE, Bl + Bz, kc);                                  \
        }

        const int rdsw = (((lane >> 4) ^ ((fr >> 1) & 3))) * 8;
        STAGE_S(0, 0);
        __syncthreads();
        for (int t = 0; t < NT; ++t) {
            const int cur = t & 1;
            const ushort* Acur = lds + cur * 4 * TILE;
            const ushort* Bcur = Acur + 2 * TILE;

            if (t + 1 < NT) STAGE_S(cur ^ 1, (t + 1) * 32);

            short8v a[4], b[4], al[4], bl[4];
#pragma unroll
            for (int m = 0; m < 4; ++m)
                a[m] = *(const short8v*)&Acur[(mw + m * 16 + fr) * 32 + rdsw];
#pragma unroll
            for (int n = 0; n < 4; ++n)
                b[n] = *(const short8v*)&Bcur[(nw + n * 16 + fr) * 32 + rdsw];
#pragma unroll
            for (int m = 0; m < 4; ++m)
                al[m] = *(const short8v*)&Acur[TILE + (mw + m * 16 + fr) * 32 + rdsw];
#pragma unroll
            for (int n = 0; n < 4; ++n)
                bl[n] = *(const short8v*)&Bcur[TILE + (nw + n * 16 + fr) * 32 + rdsw];
#pragma unroll
            for (int m = 0; m < 4; ++m)
#pragma unroll
                for (int n = 0; n < 4; ++n) {
                    acc[m][n] = __builtin_amdgcn_mfma_f32_16x16x32_bf16(a[m],  b[n],  acc[m][n], 0, 0, 0);
                    acc[m][n] = __builtin_amdgcn_mfma_f32_16x16x32_bf16(a[m],  bl[n], acc[m][n], 0, 0, 0);
                    acc[m][n] = __builtin_amdgcn_mfma_f32_16x16x32_bf16(al[m], b[n],  acc[m][n], 0, 0, 0);
                }
            __syncthreads();
        }
#undef STAGE_S
#undef STGB
#undef STG
    } else {
        // ---- BK=64, 8-slot swizzle, 2-buffer drain loop ----
        // Staging: pass p covers local rows p*32 + tid/8; LDS slot tid&7 holds
        // global 8-piece (tid&7)^(rowlocal&7) -> ds_read swizzled, bank-free.
#define STAGE64(buf, kc)                                                       \
        {                                                                      \
            const bool sec = (kc) >= ksplit;                                   \
            const int  kk  = sec ? (kc) - ksplit : (kc);                       \
            const int  lA  = sec ? lda2 : lda;                                 \
            const ushort* Asrc = sec ? A2 : Ah;                                \
            ushort* dA = lds + (buf) * 2 * TILE64;                             \
            ushort* dB = dA + TILE64;                                          \
            for (int p = 0; p < 4; ++p) {                                      \
                const int rl = p * 32 + (tid >> 3);                            \
                const int cs = ((tid & 7) ^ (rl & 7)) * 8;                     \
                long rb = j0 + rl; if (rb > Ncols - 1) rb = Ncols - 1;         \
                gload16(&Asrc[Ab + (long)(i0 + rl) * lA + kk + cs],            \
                        dA + p * 2048 + tid * 8);                              \
                gload16(&Bh[Bz + rb * ldb + (kc) + cs],                        \
                        dB + p * 2048 + tid * 8);                              \
            }                                                                  \
        }

        const int NT64 = K >> 6;
        STAGE64(0, 0);
        int cur = 0;
        for (int t = 0; t < NT64; ++t) {
            __syncthreads();   // drains prev prefetch (vmcnt 0) + read fence
            if (t + 1 < NT64) STAGE64(cur ^ 1, (t + 1) * 64);

            const ushort* Acur = lds + cur * 2 * TILE64;
            const ushort* Bcur = Acur + TILE64;
#pragma unroll
            for (int kk2 = 0; kk2 < 2; ++kk2) {
                short8v a[4], b[4];
#pragma unroll
                for (int m = 0; m < 4; ++m) {
                    const int row = mw + m * 16 + fr;
                    a[m] = *(const short8v*)&Acur[row * 64 +
                            (((kk2 * 4 + (lane >> 4)) ^ (fr & 7)) * 8)];
                }
#pragma unroll
                for (int n = 0; n < 4; ++n) {
                    const int row = nw + n * 16 + fr;
                    b[n] = *(const short8v*)&Bcur[row * 64 +
                            (((kk2 * 4 + (lane >> 4)) ^ (fr & 7)) * 8)];
                }
#pragma unroll
                for (int m = 0; m < 4; ++m)
#pragma unroll
                    for (int n = 0; n < 4; ++n)
                        acc[m][n] = __builtin_amdgcn_mfma_f32_16x16x32_bf16(a[m], b[n], acc[m][n], 0, 0, 0);
            }
            cur ^= 1;
        }
#undef STAGE64
    }

    // ---- epilogue: D[r][c]: c = lane&15, r = (lane>>4)*4 + q
    const int fc = lane & 15;
    const int fq = (lane >> 4) * 4;

    if (!SPLIT && epi == 1) {
        // LDS-transposed, coalesced row stores + fused bias/exp/rowsum.
        // TS=132 (write 2-way free); col XOR ((r&3)<<2): read 4-way -> 2-way.
        constexpr int TS = 132;
        float* T = (float*)lds;                 // [32][132] fp32, 16.9 KB
        const int r  = tid >> 3;                // 0..31
        const int cg = tid & 7;                 // 0..7
        const int csw = (r & 3) << 2;
#pragma unroll
        for (int c = 0; c < 4; ++c) {
            __syncthreads();
            if ((wave >> 1) == (c >> 1)) {
#pragma unroll
                for (int mm = 0; mm < 2; ++mm) {
                    const int m = (c & 1) * 2 + mm;
                    const int lr = mm * 16 + fq;
#pragma unroll
                    for (int n = 0; n < 4; ++n) {
                        float4v v = acc[m][n];
#pragma unroll
                        for (int q = 0; q < 4; ++q)
                            T[(lr + q) * TS +
                              ((nw + n * 16 + fc) ^ (((lr + q) & 3) << 2))] = v[q];
                    }
                }
            }
            __syncthreads();
            const int grow = i0 + 32 * c + r;
            float s = 0.f;
            float* po = &Cf[(long)grow * ldc + j0 + cg * 16];
#pragma unroll
            for (int w4 = 0; w4 < 4; ++w4) {
                const int col = cg * 16 + w4 * 4;
                const int gc = j0 + col;
                const float4 tv = *(const float4*)&T[r * TS + (col ^ csw)];
                float vv[4] = {tv.x, tv.y, tv.z, tv.w};
#pragma unroll
                for (int q2 = 0; q2 < 4; ++q2) {
                    if (gc + q2 < Ncols) {
                        vv[q2] += bias[gc + q2];
                        s += __expf(vv[q2]);
                    }
                }
                if (gc + 3 < Ncols) {
                    *(float4*)(po + w4 * 4) = make_float4(vv[0], vv[1], vv[2], vv[3]);
                } else {
#pragma unroll
                    for (int q2 = 0; q2 < 4; ++q2)
                        if (gc + q2 < Ncols) po[w4 * 4 + q2] = vv[q2];
                }
            }
            s += __shfl_xor(s, 1);
            s += __shfl_xor(s, 2);
            s += __shfl_xor(s, 4);
            if (cg == 0) atomicAdd(&aux[grow], s);
        }
        return;
    }

    float red[4][4];
#pragma unroll
    for (int m = 0; m < 4; ++m)
#pragma unroll
        for (int q = 0; q < 4; ++q) red[m][q] = 0.f;

#pragma unroll
    for (int n = 0; n < 4; ++n) {
        const int col = j0 + nw + n * 16 + fc;
        if (col >= Ncols) continue;
        const float bc = bias ? bias[col] : 0.f;
        const float wg = (epi == 2) ? Wg[col] : 0.f;
#pragma unroll
        for (int m = 0; m < 4; ++m) {
            const int r0 = i0 + mw + m * 16 + fq;
            float4v v = acc[m][n];
#pragma unroll
            for (int q = 0; q < 4; ++q) {
                float x = v[q] + bc;
                if (epi == 0) {
                    Cf[(long)bz * sC + (long)(r0 + q) * ldc + col] = x;
                } else if (epi == 2) {
                    red[m][q] += tanhf(x) * wg;
                } else {
                    C16[(long)bz * sC + (long)(r0 + q) * ldc + col] = f2bf(x);
                }
            }
        }
    }
    if (epi == 2) {
#pragma unroll
        for (int m = 0; m < 4; ++m)
#pragma unroll
            for (int q = 0; q < 4; ++q) {
                float s = red[m][q];
                s += __shfl_xor(s, 1);
                s += __shfl_xor(s, 2);
                s += __shfl_xor(s, 4);
                s += __shfl_xor(s, 8);
                if (fc == 0)
                    atomicAdd(&aux[i0 + mw + m * 16 + fq + q], s);
            }
    }
}

// ---- masked softmax over M=512, in place; also writes bf16 copy and zeroes
// ---- this row's rowsum/pgacc accumulators (runs before both GEMM consumers).
__global__ void softmax_rows(float* __restrict__ s, ushort* __restrict__ s16,
                             const int* __restrict__ msl,
                             float* __restrict__ rowsum, float* __restrict__ pgacc)
{
    __shared__ float red[256];
    const int row = blockIdx.x;
    const int b   = row / Tt;
    const int len = msl[b];
    float* p = s + (long)row * Mm;
    ushort* p16 = s16 + (long)row * Mm;
    const int tid = threadIdx.x;

    if (tid == 0) { rowsum[row] = 0.f; pgacc[row] = 0.f; }

    float v[2], mx = -INFINITY;
#pragma unroll
    for (int q = 0; q < 2; ++q) {
        int m = tid + q * 256;
        v[q] = (m < len) ? p[m] : -INFINITY;
        mx = fmaxf(mx, v[q]);
    }
    red[tid] = mx; __syncthreads();
    for (int off = 128; off > 0; off >>= 1) {
        if (tid < off) red[tid] = fmaxf(red[tid], red[tid + off]);
        __syncthreads();
    }
    mx = red[0]; __syncthreads();

    float e[2], sm = 0.f;
#pragma unroll
    for (int q = 0; q < 2; ++q) {
        int m = tid + q * 256;
        e[q] = (m < len) ? expf(v[q] - mx) : 0.f;
        sm += e[q];
    }
    red[tid] = sm; __syncthreads();
    for (int off = 128; off > 0; off >>= 1) {
        if (tid < off) red[tid] += red[tid + off];
        __syncthreads();
    }
    const float inv = 1.0f / red[0];
#pragma unroll
    for (int q = 0; q < 2; ++q) {
        float a = e[q] * inv;
        p[tid + q * 256] = a;
        p16[tid + q * 256] = f2bf(a);
    }
}

// ---- fused: pg/linv from per-row scalars; out[row][*] += linv; copy fix-up --
__launch_bounds__(256)
__global__ void shift_fix(float* __restrict__ out, const float* __restrict__ attn,
                          const float* __restrict__ pgacc, const float* __restrict__ bg,
                          const float* __restrict__ rowsum,
                          const int* __restrict__ ids, const int* __restrict__ msl)
{
    __shared__ int   ids_s[Mm];
    __shared__ float vals_s[Mm];
    const int row = blockIdx.x;
    const int b   = row / Tt;
    const int len = msl[b];
    const int tid = threadIdx.x;

    const float pgl = 1.0f / (1.0f + __expf(-(pgacc[row] + bg[0])));
    const float s = __logf(pgl / rowsum[row]);
    const float c = 1.0f - pgl;

    for (int m = tid; m < len; m += 256) {
        ids_s[m]  = ids[(long)b * Mm + m];
        vals_s[m] = attn[(long)row * Mm + m] * c;
    }

    float* p = out + (long)row * Vv;
    const int mis  = (int)(((unsigned)((long)row * Vv)) & 3u);
    const int head = (4 - mis) & 3;
    if (tid < head) p[tid] += s;
    const int nv = (Vv - head) >> 2;
    float4* p4 = (float4*)(p + head);
    for (int i = tid; i < nv; i += 256) {
        float4 v = p4[i];
        v.x += s; v.y += s; v.z += s; v.w += s;
        p4[i] = v;
    }
    const int t = head + nv * 4 + tid;
    if (t < Vv) p[t] += s;

    __syncthreads();

    for (int m = tid; m < len; m += 256) {
        const int id = ids_s[m];
        bool first = true;
        float tot = vals_s[m];
        for (int m2 = 0; m2 < len; ++m2) {
            if (ids_s[m2] == id) {
                if (m2 < m) { first = false; break; }
                if (m2 > m) tot += vals_s[m2];
            }
        }
        if (first) p[id] = __logf(__expf(p[id]) + tot);
    }
}

extern "C" void kernel_launch(void* const* d_in, const int* in_sizes, int n_in,
                              void* d_out, int out_size, void* d_ws, size_t ws_size,
                              hipStream_t stream)
{
    const float* dec = (const float*)d_in[0];
    const float* mem = (const float*)d_in[1];
    const int*   msl = (const int*)d_in[2];
    const int*   ids = (const int*)d_in[3];
    const float* Wc  = (const float*)d_in[4];
    // d_in[5] = b_copy: per-(b,t)-constant shift of scores -> softmax-invariant; skip.
    const float* Wd  = (const float*)d_in[6];
    const float* bd  = (const float*)d_in[7];
    const float* Wg  = (const float*)d_in[8];
    const float* bg  = (const float*)d_in[9];
    const float* Wo  = (const float*)d_in[10];
    const float* bo  = (const float*)d_in[11];

    float* out = (float*)d_out;

    // ---- ws layout (~107 MB) ----
    float* ws     = (float*)d_ws;
    float* attn   = ws;                          // NN*Mm fp32 (survives to shift_fix)
    float* rowsum = attn + (size_t)NN * Mm;
    float* pgacc  = rowsum + NN;
    ushort* A16   = (ushort*)(pgacc + NN);       // dec_hi  NN*Dd
    ushort* B16   = A16 + (size_t)NN * Dd;       // W_out   Vv*Dd

    // ---- d_out doubles as scratch; everything consumed before logits GEMM ----
    ushort* S      = (ushort*)d_out;
    ushort* dec_lo = S;
    ushort* WcT_hi = dec_lo + (size_t)NN * Dd;
    ushort* WcT_lo = WcT_hi + (size_t)Dd * Dd;
    ushort* mem_hi = WcT_lo + (size_t)Dd * Dd;
    ushort* mem_lo = mem_hi + (size_t)Bb * Mm * Dd;
    ushort* memT16 = mem_lo + (size_t)Bb * Mm * Dd;
    ushort* dp_hi  = memT16 + (size_t)Bb * Mm * Dd;
    ushort* dp_lo  = dp_hi + (size_t)NN * Dd;
    ushort* Wd16   = dp_lo + (size_t)NN * Dd;
    ushort* attn16 = Wd16 + (size_t)Dd * 2 * Dd;
    ushort* ao16   = attn16 + (size_t)NN * Mm;   // attn_out bf16
    float* dec_proj = (float*)(ao16 + (size_t)NN * Dd);

    // 0. precision prep
    split_cast<<<256, 256, 0, stream>>>(dec, A16, dec_lo, (long)NN * Dd / 8);
    split_cast<<<512, 256, 0, stream>>>(mem, mem_hi, mem_lo, (long)Bb * Mm * Dd / 8);
    transpose_split<<<dim3(Dd/32, Dd/32, 1), 256, 0, stream>>>(Wc, WcT_hi, WcT_lo, Dd, Dd);
    transpose_split<<<dim3(Dd/32, Mm/32, Bb), 256, 0, stream>>>(mem, memT16, nullptr, Mm, Dd);
    cast_bf16<<<512, 256, 0, stream>>>(Wd, Wd16, (long)Dd * 2 * Dd / 8);
    cast_bf16<<<2048, 256, 0, stream>>>(Wo, B16, (long)Vv * Dd / 8);

    // 1. dec_proj = dec @ W_copy^T-form (split-bf16, ~fp32 accuracy)
    gemm_mx<true><<<dim3(Dd/128, NN/128, 1), 256, 0, stream>>>(
        A16, dec_lo, WcT_hi, WcT_lo, A16, Dd, Dd, nullptr,
        dec_proj, nullptr, nullptr, nullptr,
        Dd, Dd, Dd, Dd, Dd, 0, 0, 0, 0, 0);
    split_cast<<<256, 256, 0, stream>>>(dec_proj, dp_hi, dp_lo, (long)NN * Dd / 8);

    // 2. scores[b] = dec_proj[b] @ mem[b]^T (split-bf16, batched)
    gemm_mx<true><<<dim3(Mm/128, Tt/128, Bb), 256, 0, stream>>>(
        dp_hi, dp_lo, mem_hi, mem_lo, dp_hi, Dd, Dd, nullptr,
        attn, nullptr, nullptr, nullptr,
        Mm, Dd, Dd, Dd, Mm, (long)Tt*Dd, (long)Mm*Dd, (long)Tt*Mm, 0, 0);

    // 3. masked softmax (fp32 + bf16 outputs; zeroes rowsum/pgacc)
    softmax_rows<<<NN, 256, 0, stream>>>(attn, attn16, msl, rowsum, pgacc);

    // 4. attn_out16[b] = attn[b] @ mem[b] (bf16; feeds only p_gen)
    gemm_mx<false><<<dim3(Dd/128, Tt/128, Bb), 256, 0, stream>>>(
        attn16, attn16, memT16, memT16, attn16, Mm, Mm, nullptr,
        nullptr, ao16, nullptr, nullptr,
        Dd, Mm, Mm, Mm, Dd, (long)Tt*Mm, (long)Dd*Mm, (long)Tt*Dd, 4, 0);

    // 5+6. pgacc[row] = sum_d tanh(([dec|attn_out] @ Wd^T + bd)[row,d]) * Wg[d]
    gemm_mx<false><<<dim3(Dd/128, NN/128, 1), 256, 0, stream>>>(
        A16, A16, Wd16, Wd16, ao16, Dd, Dd, bd,
        nullptr, nullptr, pgacc, Wg,
        Dd, 2*Dd, Dd, 2*Dd, 0, 0, 0, 0, 2, 0);

    // 7. logits = dec @ W_out^T + b_out -> out; rowsum += sum(exp). XCD-swizzled,
    //    BK=64 2-buffer drain loop, coalesced LDS-transpose epilogue.
    gemm_mx<false><<<8 * 8 * DIV_UP(DIV_UP(Vv,128), 8), 256, 0, stream>>>(
        A16, A16, B16, B16, A16, Dd, Dd, bo,
        out, nullptr, rowsum, nullptr,
        Vv, Dd, Dd, Dd, Vv, 0, 0, 0, 1, DIV_UP(Vv,128));

    // 8. fused pg/linv + shift + copy fix-up
    shift_fix<<<NN, 256, 0, stream>>>(out, attn, pgacc, bg, rowsum, ids, msl);
}

// Round 13
// 659.990 us; speedup vs baseline: 1.1079x; 1.0407x over previous
//
#include <hip/hip_runtime.h>
#include <math.h>

#define DIV_UP(a,b) (((a)+(b)-1)/(b))

static constexpr int Bb = 4, Tt = 256, Mm = 512, Dd = 1024, Vv = 50257;
static constexpr int NN = Bb * Tt;   // 1024 flattened (b,t) rows

typedef __attribute__((ext_vector_type(8))) short short8v;
typedef __attribute__((ext_vector_type(4))) float float4v;
typedef unsigned short ushort;

// fp32 -> bf16 RNE (bit trick, branchless)
static __device__ __forceinline__ ushort f2bf(float f) {
    unsigned u = __float_as_uint(f);
    u += 0x7FFFu + ((u >> 16) & 1u);
    return (ushort)(u >> 16);
}
static __device__ __forceinline__ float bf2f(ushort h) {
    return __uint_as_float(((unsigned)h) << 16);
}

// async 16B global -> LDS (wave-uniform base + lane*16 dest)
static __device__ __forceinline__ void gload16(const void* g, void* l) {
    __builtin_amdgcn_global_load_lds(
        (const __attribute__((address_space(1))) unsigned int*)g,
        (__attribute__((address_space(3))) unsigned int*)l, 16, 0, 0);
}

// ---- fp32 -> bf16 cast, 8/thread --------------------------------------------
__launch_bounds__(256)
__global__ void cast_bf16(const float* __restrict__ src, ushort* __restrict__ dst, long n8)
{
    for (long i = blockIdx.x * 256 + threadIdx.x; i < n8; i += (long)gridDim.x * 256) {
        const float4 v0 = *(const float4*)&src[i * 8];
        const float4 v1 = *(const float4*)&src[i * 8 + 4];
        short8v t;
        t[0]=f2bf(v0.x); t[1]=f2bf(v0.y); t[2]=f2bf(v0.z); t[3]=f2bf(v0.w);
        t[4]=f2bf(v1.x); t[5]=f2bf(v1.y); t[6]=f2bf(v1.z); t[7]=f2bf(v1.w);
        *(short8v*)&dst[i * 8] = t;
    }
}

// ---- fp32 -> (hi, lo) bf16 split, 8/thread ----------------------------------
__launch_bounds__(256)
__global__ void split_cast(const float* __restrict__ src, ushort* __restrict__ hi,
                           ushort* __restrict__ lo, long n8)
{
    for (long i = blockIdx.x * 256 + threadIdx.x; i < n8; i += (long)gridDim.x * 256) {
        short8v th, tl;
#pragma unroll
        for (int q = 0; q < 8; ++q) {
            float v = src[i * 8 + q];
            ushort h = f2bf(v);
            th[q] = h;
            tl[q] = f2bf(v - bf2f(h));
        }
        *(short8v*)&hi[i * 8] = th;
        *(short8v*)&lo[i * 8] = tl;
    }
}

// ---- batched transpose: in[b] R x C fp32 -> out[b] C x R bf16 (hi, opt lo) --
__launch_bounds__(256)
__global__ void transpose_split(const float* __restrict__ in, ushort* __restrict__ oh,
                                ushort* __restrict__ ol, int R, int C)
{
    __shared__ float t[32][33];
    const int bz = blockIdx.z;
    in += (long)bz * R * C;
    oh += (long)bz * R * C;
    if (ol) ol += (long)bz * R * C;
    const int tx = threadIdx.x & 31, ty = threadIdx.x >> 5;
    const int r0 = blockIdx.y * 32, c0 = blockIdx.x * 32;
#pragma unroll
    for (int k = 0; k < 4; ++k)
        t[ty + k * 8][tx] = in[(long)(r0 + ty + k * 8) * C + c0 + tx];
    __syncthreads();
#pragma unroll
    for (int k = 0; k < 4; ++k) {
        float v = t[tx][ty + k * 8];
        ushort h = f2bf(v);
        long o = (long)(c0 + ty + k * 8) * R + r0 + tx;
        oh[o] = h;
        if (ol) ol[o] = f2bf(v - bf2f(h));
    }
}

// ---------------------------------------------------------------------------
// Unified bf16 MFMA GEMM (NT): C[i,j] = sum_k A[i,k]*B[j,k]
// Proven 2-buffer drain loop (K5 structure), BK=32, 4-slot XOR source swizzle.
// SPLIT: 3-pass split-bf16 (Ah*Bh + Ah*Bl + Al*Bh).
// MREP: wave M-fragments; block tile = (MREP*32) x 128. MREP=2 doubles the
//   grid for the small GEMMs (latency-bound at 64-block grids).
// epi: 0 = fp32 C; 1 = fp32 C + bias + rowsum[i] += sum_j exp(x) via
//      LDS-transposed coalesced stores (TS=132 + col-XOR);
//      2 = pgacc[i] += sum tanh(x+b)*Wg; 3 = split hi/lo bf16 C write;
//      4 = bf16 C write.
// xcd_jtiles > 0: flat-grid XCD swizzle (8 M-tiles fast per XCD chunk).
// ---------------------------------------------------------------------------
template<bool SPLIT, int MREP>
__launch_bounds__(256)
__global__ void gemm_mx(const ushort* __restrict__ Ah, const ushort* __restrict__ Al,
                        const ushort* __restrict__ Bh, const ushort* __restrict__ Bl,
                        const ushort* __restrict__ A2, int ksplit, int lda2,
                        const float* __restrict__ bias,
                        float* __restrict__ Cf, ushort* __restrict__ C16,
                        float* __restrict__ aux, const float* __restrict__ Wg,
                        int Ncols, int K, int lda, int ldb, int ldc,
                        long sA, long sB, long sC, int epi, int xcd_jtiles)
{
    constexpr int BM    = MREP * 32;        // block rows
    constexpr int ATILE = BM * 32;          // ushorts per A tile (BM x 32)
    constexpr int BTILE = 4096;             // 128 x 32
    constexpr int BUF   = (SPLIT ? 2 : 1) * (ATILE + BTILE);
    __shared__ __align__(16) ushort lds[2 * BUF];

    int mt, jt, bz;
    if (xcd_jtiles > 0) {
        const int id = blockIdx.x;
        const int s = id >> 3;
        jt = (id & 7) * ((xcd_jtiles + 7) >> 3) + (s >> 3);
        mt = s & 7;
        bz = 0;
        if (jt >= xcd_jtiles) return;
    } else { jt = blockIdx.x; mt = blockIdx.y; bz = blockIdx.z; }

    const int tid  = threadIdx.x;
    const int lane = tid & 63;
    const int wave = tid >> 6;
    const int mw = (wave >> 1) * (MREP * 16), nw = (wave & 1) * 64;
    const int i0 = mt * BM, j0 = jt * 128;

    const int srow = tid >> 2;                              // 0..63
    const int soff = ((tid & 3) ^ ((srow >> 1) & 3)) * 8;   // swizzled source slot

    const long Ab = (long)bz * sA;
    const long Bz = (long)bz * sB;
    const long ar0 = i0 + srow, ar1 = i0 + 64 + srow;       // ar1 used iff MREP==4
    long br0 = j0 + srow;      if (br0 > Ncols - 1) br0 = Ncols - 1;
    long br1 = j0 + 64 + srow; if (br1 > Ncols - 1) br1 = Ncols - 1;

    const int NT = K >> 5;
    const int fr = lane & 15;
    const int rdsw = ((lane >> 4) ^ ((fr >> 1) & 3)) * 8;   // swizzled read slot

    float4v acc[MREP][4];
#pragma unroll
    for (int m = 0; m < MREP; ++m)
#pragma unroll
        for (int n = 0; n < 4; ++n) acc[m][n] = (float4v){0.f, 0.f, 0.f, 0.f};

    auto STAGE = [&](int buf, int kc) {
        ushort* base = lds + buf * BUF;
        if constexpr (SPLIT) {
            const ushort* pAh = Ah + Ab; const ushort* pAl = Al + Ab;
            const ushort* pBh = Bh + Bz; const ushort* pBl = Bl + Bz;
            gload16(&pAh[ar0 * lda + kc + soff], base + tid * 8);
            if constexpr (MREP == 4)
                gload16(&pAh[ar1 * lda + kc + soff], base + 2048 + tid * 8);
            ushort* bAl = base + ATILE;
            gload16(&pAl[ar0 * lda + kc + soff], bAl + tid * 8);
            if constexpr (MREP == 4)
                gload16(&pAl[ar1 * lda + kc + soff], bAl + 2048 + tid * 8);
            ushort* bBh = base + 2 * ATILE;
            gload16(&pBh[br0 * ldb + kc + soff], bBh + tid * 8);
            gload16(&pBh[br1 * ldb + kc + soff], bBh + 2048 + tid * 8);
            ushort* bBl = bBh + BTILE;
            gload16(&pBl[br0 * ldb + kc + soff], bBl + tid * 8);
            gload16(&pBl[br1 * ldb + kc + soff], bBl + 2048 + tid * 8);
        } else {
            const bool sec = kc >= ksplit;
            const int  kk  = sec ? kc - ksplit : kc;
            const int  lA  = sec ? lda2 : lda;
            const ushort* Asrc = (sec ? A2 : Ah) + Ab;
            gload16(&Asrc[ar0 * (long)lA + kk + soff], base + tid * 8);
            if constexpr (MREP == 4)
                gload16(&Asrc[ar1 * (long)lA + kk + soff], base + 2048 + tid * 8);
            ushort* bB = base + ATILE;
            const ushort* pB = Bh + Bz;
            gload16(&pB[br0 * ldb + kc + soff], bB + tid * 8);
            gload16(&pB[br1 * ldb + kc + soff], bB + 2048 + tid * 8);
        }
    };

    // ---- proven 2-buffer drain loop (K5) ----
    STAGE(0, 0);
    __syncthreads();
    for (int t = 0; t < NT; ++t) {
        const int cur = t & 1;
        const ushort* Acur = lds + cur * BUF;
        const ushort* Bcur = Acur + (SPLIT ? 2 * ATILE : ATILE);

        if (t + 1 < NT) STAGE(cur ^ 1, (t + 1) * 32);

        short8v a[MREP], b[4];
#pragma unroll
        for (int m = 0; m < MREP; ++m)
            a[m] = *(const short8v*)&Acur[(mw + m * 16 + fr) * 32 + rdsw];
#pragma unroll
        for (int n = 0; n < 4; ++n)
            b[n] = *(const short8v*)&Bcur[(nw + n * 16 + fr) * 32 + rdsw];

        if constexpr (SPLIT) {
            short8v al[MREP], bl[4];
#pragma unroll
            for (int m = 0; m < MREP; ++m)
                al[m] = *(const short8v*)&Acur[ATILE + (mw + m * 16 + fr) * 32 + rdsw];
#pragma unroll
            for (int n = 0; n < 4; ++n)
                bl[n] = *(const short8v*)&Bcur[BTILE + (nw + n * 16 + fr) * 32 + rdsw];
#pragma unroll
            for (int m = 0; m < MREP; ++m)
#pragma unroll
                for (int n = 0; n < 4; ++n) {
                    acc[m][n] = __builtin_amdgcn_mfma_f32_16x16x32_bf16(a[m],  b[n],  acc[m][n], 0, 0, 0);
                    acc[m][n] = __builtin_amdgcn_mfma_f32_16x16x32_bf16(a[m],  bl[n], acc[m][n], 0, 0, 0);
                    acc[m][n] = __builtin_amdgcn_mfma_f32_16x16x32_bf16(al[m], b[n],  acc[m][n], 0, 0, 0);
                }
        } else {
#pragma unroll
            for (int m = 0; m < MREP; ++m)
#pragma unroll
                for (int n = 0; n < 4; ++n)
                    acc[m][n] = __builtin_amdgcn_mfma_f32_16x16x32_bf16(a[m], b[n], acc[m][n], 0, 0, 0);
        }
        __syncthreads();
    }

    // ---- epilogue: D[r][c]: c = lane&15, r = (lane>>4)*4 + q
    const int fc = lane & 15;
    const int fq = (lane >> 4) * 4;

    if constexpr (!SPLIT && MREP == 4) {
        if (epi == 1) {
            // LDS-transposed, coalesced row stores + fused bias/exp/rowsum.
            // TS=132 (write 2-way free); col XOR ((r&3)<<2): read 4-way -> 2-way.
            constexpr int TS = 132;
            float* T = (float*)lds;                 // [32][132] fp32, 16.9 KB
            const int r  = tid >> 3;                // 0..31
            const int cg = tid & 7;                 // 0..7
            const int csw = (r & 3) << 2;
#pragma unroll
            for (int c = 0; c < 4; ++c) {
                __syncthreads();
                if ((wave >> 1) == (c >> 1)) {
#pragma unroll
                    for (int mm = 0; mm < 2; ++mm) {
                        const int m = (c & 1) * 2 + mm;
                        const int lr = mm * 16 + fq;
#pragma unroll
                        for (int n = 0; n < 4; ++n) {
                            float4v v = acc[m][n];
#pragma unroll
                            for (int q = 0; q < 4; ++q)
                                T[(lr + q) * TS +
                                  ((nw + n * 16 + fc) ^ (((lr + q) & 3) << 2))] = v[q];
                        }
                    }
                }
                __syncthreads();
                const int grow = i0 + 32 * c + r;
                float s = 0.f;
                float* po = &Cf[(long)grow * ldc + j0 + cg * 16];
#pragma unroll
                for (int w4 = 0; w4 < 4; ++w4) {
                    const int col = cg * 16 + w4 * 4;
                    const int gc = j0 + col;
                    const float4 tv = *(const float4*)&T[r * TS + (col ^ csw)];
                    float vv[4] = {tv.x, tv.y, tv.z, tv.w};
#pragma unroll
                    for (int q2 = 0; q2 < 4; ++q2) {
                        if (gc + q2 < Ncols) {
                            vv[q2] += bias[gc + q2];
                            s += __expf(vv[q2]);
                        }
                    }
                    if (gc + 3 < Ncols) {
                        *(float4*)(po + w4 * 4) = make_float4(vv[0], vv[1], vv[2], vv[3]);
                    } else {
#pragma unroll
                        for (int q2 = 0; q2 < 4; ++q2)
                            if (gc + q2 < Ncols) po[w4 * 4 + q2] = vv[q2];
                    }
                }
                s += __shfl_xor(s, 1);
                s += __shfl_xor(s, 2);
                s += __shfl_xor(s, 4);
                if (cg == 0) atomicAdd(&aux[grow], s);
            }
            return;
        }
    }

    float red[4][4];
#pragma unroll
    for (int m = 0; m < 4; ++m)
#pragma unroll
        for (int q = 0; q < 4; ++q) red[m][q] = 0.f;

    ushort* lo16 = (ushort*)aux;   // epi=3 low-half destination

#pragma unroll
    for (int n = 0; n < 4; ++n) {
        const int col = j0 + nw + n * 16 + fc;
        if (col >= Ncols) continue;
        const float bc = bias ? bias[col] : 0.f;
        const float wg = (epi == 2) ? Wg[col] : 0.f;
#pragma unroll
        for (int m = 0; m < MREP; ++m) {
            const int r0 = i0 + mw + m * 16 + fq;
            float4v v = acc[m][n];
#pragma unroll
            for (int q = 0; q < 4; ++q) {
                float x = v[q] + bc;
                const long ci = (long)bz * sC + (long)(r0 + q) * ldc + col;
                if (epi == 0) {
                    Cf[ci] = x;
                } else if (epi == 2) {
                    red[m][q] += tanhf(x) * wg;
                } else if (epi == 3) {
                    ushort h = f2bf(x);
                    C16[ci] = h;
                    lo16[ci] = f2bf(x - bf2f(h));
                } else {
                    C16[ci] = f2bf(x);
                }
            }
        }
    }
    if (epi == 2) {
#pragma unroll
        for (int m = 0; m < MREP; ++m)
#pragma unroll
            for (int q = 0; q < 4; ++q) {
                float s = red[m][q];
                s += __shfl_xor(s, 1);
                s += __shfl_xor(s, 2);
                s += __shfl_xor(s, 4);
                s += __shfl_xor(s, 8);
                if (fc == 0)
                    atomicAdd(&aux[i0 + mw + m * 16 + fq + q], s);
            }
    }
}

// ---- masked softmax over M=512, in place; also writes bf16 copy and zeroes
// ---- this row's rowsum/pgacc accumulators (runs before both GEMM consumers).
__global__ void softmax_rows(float* __restrict__ s, ushort* __restrict__ s16,
                             const int* __restrict__ msl,
                             float* __restrict__ rowsum, float* __restrict__ pgacc)
{
    __shared__ float red[256];
    const int row = blockIdx.x;
    const int b   = row / Tt;
    const int len = msl[b];
    float* p = s + (long)row * Mm;
    ushort* p16 = s16 + (long)row * Mm;
    const int tid = threadIdx.x;

    if (tid == 0) { rowsum[row] = 0.f; pgacc[row] = 0.f; }

    float v[2], mx = -INFINITY;
#pragma unroll
    for (int q = 0; q < 2; ++q) {
        int m = tid + q * 256;
        v[q] = (m < len) ? p[m] : -INFINITY;
        mx = fmaxf(mx, v[q]);
    }
    red[tid] = mx; __syncthreads();
    for (int off = 128; off > 0; off >>= 1) {
        if (tid < off) red[tid] = fmaxf(red[tid], red[tid + off]);
        __syncthreads();
    }
    mx = red[0]; __syncthreads();

    float e[2], sm = 0.f;
#pragma unroll
    for (int q = 0; q < 2; ++q) {
        int m = tid + q * 256;
        e[q] = (m < len) ? expf(v[q] - mx) : 0.f;
        sm += e[q];
    }
    red[tid] = sm; __syncthreads();
    for (int off = 128; off > 0; off >>= 1) {
        if (tid < off) red[tid] += red[tid + off];
        __syncthreads();
    }
    const float inv = 1.0f / red[0];
#pragma unroll
    for (int q = 0; q < 2; ++q) {
        float a = e[q] * inv;
        p[tid + q * 256] = a;
        p16[tid + q * 256] = f2bf(a);
    }
}

// ---- fused: pg/linv from per-row scalars; out[row][*] += linv; copy fix-up --
__launch_bounds__(256)
__global__ void shift_fix(float* __restrict__ out, const float* __restrict__ attn,
                          const float* __restrict__ pgacc, const float* __restrict__ bg,
                          const float* __restrict__ rowsum,
                          const int* __restrict__ ids, const int* __restrict__ msl)
{
    __shared__ int   ids_s[Mm];
    __shared__ float vals_s[Mm];
    const int row = blockIdx.x;
    const int b   = row / Tt;
    const int len = msl[b];
    const int tid = threadIdx.x;

    const float pgl = 1.0f / (1.0f + __expf(-(pgacc[row] + bg[0])));
    const float s = __logf(pgl / rowsum[row]);
    const float c = 1.0f - pgl;

    for (int m = tid; m < len; m += 256) {
        ids_s[m]  = ids[(long)b * Mm + m];
        vals_s[m] = attn[(long)row * Mm + m] * c;
    }

    float* p = out + (long)row * Vv;
    const int mis  = (int)(((unsigned)((long)row * Vv)) & 3u);
    const int head = (4 - mis) & 3;
    if (tid < head) p[tid] += s;
    const int nv = (Vv - head) >> 2;
    float4* p4 = (float4*)(p + head);
    for (int i = tid; i < nv; i += 256) {
        float4 v = p4[i];
        v.x += s; v.y += s; v.z += s; v.w += s;
        p4[i] = v;
    }
    const int t = head + nv * 4 + tid;
    if (t < Vv) p[t] += s;

    __syncthreads();

    for (int m = tid; m < len; m += 256) {
        const int id = ids_s[m];
        bool first = true;
        float tot = vals_s[m];
        for (int m2 = 0; m2 < len; ++m2) {
            if (ids_s[m2] == id) {
                if (m2 < m) { first = false; break; }
                if (m2 > m) tot += vals_s[m2];
            }
        }
        if (first) p[id] = __logf(__expf(p[id]) + tot);
    }
}

extern "C" void kernel_launch(void* const* d_in, const int* in_sizes, int n_in,
                              void* d_out, int out_size, void* d_ws, size_t ws_size,
                              hipStream_t stream)
{
    const float* dec = (const float*)d_in[0];
    const float* mem = (const float*)d_in[1];
    const int*   msl = (const int*)d_in[2];
    const int*   ids = (const int*)d_in[3];
    const float* Wc  = (const float*)d_in[4];
    // d_in[5] = b_copy: per-(b,t)-constant shift of scores -> softmax-invariant; skip.
    const float* Wd  = (const float*)d_in[6];
    const float* bd  = (const float*)d_in[7];
    const float* Wg  = (const float*)d_in[8];
    const float* bg  = (const float*)d_in[9];
    const float* Wo  = (const float*)d_in[10];
    const float* bo  = (const float*)d_in[11];

    float* out = (float*)d_out;

    // ---- ws layout (~107 MB) ----
    float* ws     = (float*)d_ws;
    float* attn   = ws;                          // NN*Mm fp32 (survives to shift_fix)
    float* rowsum = attn + (size_t)NN * Mm;
    float* pgacc  = rowsum + NN;
    ushort* A16   = (ushort*)(pgacc + NN);       // dec_hi  NN*Dd
    ushort* B16   = A16 + (size_t)NN * Dd;       // W_out   Vv*Dd

    // ---- d_out doubles as scratch; everything consumed before logits GEMM ----
    ushort* S      = (ushort*)d_out;
    ushort* dec_lo = S;
    ushort* WcT_hi = dec_lo + (size_t)NN * Dd;
    ushort* WcT_lo = WcT_hi + (size_t)Dd * Dd;
    ushort* mem_hi = WcT_lo + (size_t)Dd * Dd;
    ushort* mem_lo = mem_hi + (size_t)Bb * Mm * Dd;
    ushort* memT16 = mem_lo + (size_t)Bb * Mm * Dd;
    ushort* dp_hi  = memT16 + (size_t)Bb * Mm * Dd;
    ushort* dp_lo  = dp_hi + (size_t)NN * Dd;
    ushort* Wd16   = dp_lo + (size_t)NN * Dd;
    ushort* attn16 = Wd16 + (size_t)Dd * 2 * Dd;
    ushort* ao16   = attn16 + (size_t)NN * Mm;   // attn_out bf16

    // 0. precision prep
    split_cast<<<256, 256, 0, stream>>>(dec, A16, dec_lo, (long)NN * Dd / 8);
    split_cast<<<512, 256, 0, stream>>>(mem, mem_hi, mem_lo, (long)Bb * Mm * Dd / 8);
    transpose_split<<<dim3(Dd/32, Dd/32, 1), 256, 0, stream>>>(Wc, WcT_hi, WcT_lo, Dd, Dd);
    transpose_split<<<dim3(Dd/32, Mm/32, Bb), 256, 0, stream>>>(mem, memT16, nullptr, Mm, Dd);
    cast_bf16<<<512, 256, 0, stream>>>(Wd, Wd16, (long)Dd * 2 * Dd / 8);
    cast_bf16<<<2048, 256, 0, stream>>>(Wo, B16, (long)Vv * Dd / 8);

    // 1. dp = dec @ W_copy^T-form (split-bf16); epilogue writes hi/lo directly
    gemm_mx<true,2><<<dim3(Dd/128, NN/64, 1), 256, 0, stream>>>(
        A16, dec_lo, WcT_hi, WcT_lo, A16, Dd, Dd, nullptr,
        nullptr, dp_hi, (float*)dp_lo, nullptr,
        Dd, Dd, Dd, Dd, Dd, 0, 0, 0, 3, 0);

    // 2. scores[b] = dp[b] @ mem[b]^T (split-bf16, batched)
    gemm_mx<true,2><<<dim3(Mm/128, Tt/64, Bb), 256, 0, stream>>>(
        dp_hi, dp_lo, mem_hi, mem_lo, dp_hi, Dd, Dd, nullptr,
        attn, nullptr, nullptr, nullptr,
        Mm, Dd, Dd, Dd, Mm, (long)Tt*Dd, (long)Mm*Dd, (long)Tt*Mm, 0, 0);

    // 3. masked softmax (fp32 + bf16 outputs; zeroes rowsum/pgacc)
    softmax_rows<<<NN, 256, 0, stream>>>(attn, attn16, msl, rowsum, pgacc);

    // 4. attn_out16[b] = attn[b] @ mem[b] (bf16; feeds only p_gen)
    gemm_mx<false,2><<<dim3(Dd/128, Tt/64, Bb), 256, 0, stream>>>(
        attn16, attn16, memT16, memT16, attn16, Mm, Mm, nullptr,
        nullptr, ao16, nullptr, nullptr,
        Dd, Mm, Mm, Mm, Dd, (long)Tt*Mm, (long)Dd*Mm, (long)Tt*Dd, 4, 0);

    // 5+6. pgacc[row] = sum_d tanh(([dec|attn_out] @ Wd^T + bd)[row,d]) * Wg[d]
    gemm_mx<false,2><<<dim3(Dd/128, NN/64, 1), 256, 0, stream>>>(
        A16, A16, Wd16, Wd16, ao16, Dd, Dd, bd,
        nullptr, nullptr, pgacc, Wg,
        Dd, 2*Dd, Dd, 2*Dd, 0, 0, 0, 0, 2, 0);

    // 7. logits = dec @ W_out^T + b_out -> out; rowsum += sum(exp).
    //    K5 loop (BK=32, 32 KB) + XCD swizzle + TS132/colXOR epilogue.
    gemm_mx<false,4><<<8 * 8 * DIV_UP(DIV_UP(Vv,128), 8), 256, 0, stream>>>(
        A16, A16, B16, B16, A16, Dd, Dd, bo,
        out, nullptr, rowsum, nullptr,
        Vv, Dd, Dd, Dd, Vv, 0, 0, 0, 1, DIV_UP(Vv,128));

    // 8. fused pg/linv + shift + copy fix-up
    shift_fix<<<NN, 256, 0, stream>>>(out, attn, pgacc, bg, rowsum, ids, msl);
}